// Round 1
// baseline (1092.544 us; speedup 1.0000x reference)
//
#include <hip/hip_runtime.h>

#define NN 50000
#define EE 800000
#define HIDD 96
#define NPROJ 104

__device__ __forceinline__ float warp_max64(float v){
  #pragma unroll
  for(int m=1;m<64;m<<=1) v=fmaxf(v,__shfl_xor(v,m));
  return v;
}
__device__ __forceinline__ float warp_sum64(float v){
  #pragma unroll
  for(int m=1;m<64;m<<=1) v+=__shfl_xor(v,m);
  return v;
}

// ---------- CSR build ----------
__global__ void k_deg(const int* __restrict__ dst, const float* __restrict__ eattr,
                      int* __restrict__ deg, float* __restrict__ lattr){
  int e=blockIdx.x*blockDim.x+threadIdx.x;
  if(e>=EE) return;
  int d=dst[e];
  atomicAdd(&deg[d],1);
  float4 ea=*(const float4*)(eattr+(size_t)e*4);
  atomicAdd(&lattr[(size_t)d*4+0],ea.x);
  atomicAdd(&lattr[(size_t)d*4+1],ea.y);
  atomicAdd(&lattr[(size_t)d*4+2],ea.z);
  atomicAdd(&lattr[(size_t)d*4+3],ea.w);
}

__global__ void k_scan1(const int* __restrict__ deg, int* __restrict__ off, int* __restrict__ part){
  __shared__ int sd[256];
  int t=threadIdx.x, b=blockIdx.x;
  int base=b*1024+t*4;
  int v0=(base+0<NN)?deg[base+0]:0;
  int v1=(base+1<NN)?deg[base+1]:0;
  int v2=(base+2<NN)?deg[base+2]:0;
  int v3=(base+3<NN)?deg[base+3]:0;
  int s=v0+v1+v2+v3;
  sd[t]=s; __syncthreads();
  for(int o=1;o<256;o<<=1){
    int x=(t>=o)?sd[t-o]:0;
    __syncthreads();
    sd[t]+=x;
    __syncthreads();
  }
  int ep=sd[t]-s;
  if(base+0<NN) off[base+0]=ep;
  if(base+1<NN) off[base+1]=ep+v0;
  if(base+2<NN) off[base+2]=ep+v0+v1;
  if(base+3<NN) off[base+3]=ep+v0+v1+v2;
  if(t==255) part[b]=sd[255];
}

__global__ void k_scan2(int* part, int* off, int nb){
  if(threadIdx.x==0&&blockIdx.x==0){
    int run=0;
    for(int i=0;i<nb;i++){ int x=part[i]; part[i]=run; run+=x; }
    off[NN]=run;
  }
}

__global__ void k_scan3(const int* __restrict__ part, int* __restrict__ off, int* __restrict__ cur){
  int i=blockIdx.x*blockDim.x+threadIdx.x;
  if(i<NN){ int v=off[i]+part[i>>10]; off[i]=v; cur[i]=v; }
}

__global__ void k_scatter(const int* __restrict__ src, const int* __restrict__ dst,
                          const float* __restrict__ eattr, int* __restrict__ cur,
                          int* __restrict__ ssrc, float* __restrict__ sea){
  int e=blockIdx.x*blockDim.x+threadIdx.x;
  if(e>=EE) return;
  int d=dst[e];
  int p=atomicAdd(&cur[d],1);
  ssrc[p]=src[e];
  *(float4*)(sea+(size_t)p*4)=*(const float4*)(eattr+(size_t)e*4);
}

// ---------- per-layer weight prep: Wext = [W | W.a_src | W.a_dst], M = We.a_edge ----------
__global__ void k_prepw(const float* __restrict__ conv_w, const float* __restrict__ a_src,
                        const float* __restrict__ a_dst, const float* __restrict__ lin_e,
                        const float* __restrict__ a_e,
                        float* __restrict__ Wext, float* __restrict__ Mm){
  int t=blockIdx.x*blockDim.x+threadIdx.x;
  const int WTOT=4*96*104;
  if(t<WTOT){
    int l=t/(96*104); int rem=t-l*(96*104); int k=rem/104; int j=rem-k*104;
    const float* W=conv_w+(size_t)l*96*96+(size_t)k*96;
    float v;
    if(j<96) v=W[j];
    else if(j<100){ int hh=j-96; const float* a=a_src+l*96+hh*24; v=0.f;
      #pragma unroll
      for(int c=0;c<24;c++) v+=W[hh*24+c]*a[c]; }
    else { int hh=j-100; const float* a=a_dst+l*96+hh*24; v=0.f;
      #pragma unroll
      for(int c=0;c<24;c++) v+=W[hh*24+c]*a[c]; }
    Wext[t]=v;
  } else if(t<WTOT+64){
    int q=t-WTOT; int l=q>>4; int i=(q>>2)&3; int hh=q&3;
    const float* We=lin_e+(size_t)l*4*96+(size_t)i*96;
    const float* a=a_e+l*96+hh*24;
    float v=0.f;
    #pragma unroll
    for(int c=0;c<24;c++) v+=We[hh*24+c]*a[c];
    Mm[q]=v;  // M[l][i][h]
  }
}

// ---------- input MLP layer 1 : hid1 = relu(x @ w1 + b1) ----------
__global__ void k_mlp1(const float* __restrict__ x, const float* __restrict__ w,
                       const float* __restrict__ b, float* __restrict__ out){
  int i=blockIdx.x*blockDim.x+threadIdx.x;
  if(i>=NN) return;
  float xv[12];
  #pragma unroll
  for(int k=0;k<12;k++) xv[k]=x[(size_t)i*12+k];
  for(int j=0;j<HIDD;j++){
    float a=b[j];
    #pragma unroll
    for(int k=0;k<12;k++) a+=xv[k]*w[k*HIDD+j];
    out[(size_t)i*HIDD+j]=fmaxf(a,0.f);
  }
}

// ---------- generic tiled GEMM: C[N][NC] = A[N][96] @ W[96][NC] (+bias) ----------
template<int NC>
__global__ __launch_bounds__(256) void k_gemm(const float* __restrict__ A, const float* __restrict__ W,
                                              const float* __restrict__ bias, float* __restrict__ C){
  __shared__ float As[64*96];
  __shared__ float Ws[96*NC];
  int t=threadIdx.x;
  int r0=blockIdx.x*64;
  for(int i=t;i<96*NC;i+=256) Ws[i]=W[i];
  for(int i=t;i<64*96;i+=256){
    int rr=i/96, cc=i-rr*96; int g=r0+rr;
    As[i]=(g<NN)?A[(size_t)g*96+cc]:0.f;
  }
  __syncthreads();
  int r=t>>2, cq=t&3;
  constexpr int NPC=NC/4;
  float acc[NPC];
  #pragma unroll
  for(int i=0;i<NPC;i++) acc[i]=0.f;
  for(int k=0;k<96;k++){
    float a=As[r*96+k];
    #pragma unroll
    for(int i=0;i<NPC;i++) acc[i]+=a*Ws[k*NC+cq+4*i];
  }
  int g=r0+r;
  if(g<NN){
    #pragma unroll
    for(int i=0;i<NPC;i++){ int j=cq+4*i; C[(size_t)g*NC+j]=acc[i]+(bias?bias[j]:0.f); }
  }
}

// ---------- fused GAT aggregation + bias + ELU + residual + LayerNorm ----------
// one 64-lane wave per node; hproj[n] = [96 proj | a_src(4) | a_dst(4)]
__global__ __launch_bounds__(256) void k_agg(const float* __restrict__ hproj, float* __restrict__ h,
    const int* __restrict__ off, const int* __restrict__ ssrc, const float* __restrict__ sea,
    const float* __restrict__ lattr, const float* __restrict__ Mm,
    const float* __restrict__ bias, const float* __restrict__ nsc, const float* __restrict__ nbi){
  int wid=threadIdx.x>>6, lane=threadIdx.x&63;
  int n=blockIdx.x*4+wid;
  if(n>=NN) return;
  float M[16];
  #pragma unroll
  for(int i=0;i<16;i++) M[i]=Mm[i];
  const float4 ad=*(const float4*)(hproj+(size_t)n*NPROJ+100);
  int b0=off[n]; int deg=off[n+1]-b0; int tot=deg+1;
  float invdeg=1.f/(float)(deg>0?deg:1);
  float m0=-INFINITY,m1=-INFINITY,m2=-INFINITY,m3=-INFINITY;
  float d0=0.f,d1=0.f,d2=0.f,d3=0.f;
  float acc0=0.f, acc1=0.f;
  int h0s=lane/24;        // head of dim 'lane' (0..2)
  int h1s=(64+lane)/24;   // head of dim 64+lane (2 or 3)
  for(int cs=0;cs<tot;cs+=64){
    int idx=cs+lane;
    bool valid=idx<tot;
    float a0=-INFINITY,a1=-INFINITY,a2=-INFINITY,a3=-INFINITY;
    int sj=n;
    if(valid){
      float4 ea;
      if(idx<deg){ int ei=b0+idx; sj=ssrc[ei]; ea=*(const float4*)(sea+(size_t)ei*4); }
      else { ea=*(const float4*)(lattr+(size_t)n*4); ea.x*=invdeg; ea.y*=invdeg; ea.z*=invdeg; ea.w*=invdeg; }
      const float4 as=*(const float4*)(hproj+(size_t)sj*NPROJ+96);
      a0=as.x+ad.x+ea.x*M[0]+ea.y*M[4]+ea.z*M[8] +ea.w*M[12];
      a1=as.y+ad.y+ea.x*M[1]+ea.y*M[5]+ea.z*M[9] +ea.w*M[13];
      a2=as.z+ad.z+ea.x*M[2]+ea.y*M[6]+ea.z*M[10]+ea.w*M[14];
      a3=as.w+ad.w+ea.x*M[3]+ea.y*M[7]+ea.z*M[11]+ea.w*M[15];
      a0=a0>0.f?a0:0.2f*a0; a1=a1>0.f?a1:0.2f*a1;
      a2=a2>0.f?a2:0.2f*a2; a3=a3>0.f?a3:0.2f*a3;
    }
    float c0=warp_max64(a0),c1=warp_max64(a1),c2=warp_max64(a2),c3=warp_max64(a3);
    float nm0=fmaxf(m0,c0),nm1=fmaxf(m1,c1),nm2=fmaxf(m2,c2),nm3=fmaxf(m3,c3);
    float s0=expf(m0-nm0),s1=expf(m1-nm1),s2=expf(m2-nm2),s3=expf(m3-nm3);
    d0*=s0; d1*=s1; d2*=s2; d3*=s3;
    float scA=(h0s==0)?s0:((h0s==1)?s1:s2);
    acc0*=scA;
    float scB=(h1s==2)?s2:s3;
    acc1*=scB;
    m0=nm0;m1=nm1;m2=nm2;m3=nm3;
    float e0=valid?expf(a0-nm0):0.f;
    float e1=valid?expf(a1-nm1):0.f;
    float e2=valid?expf(a2-nm2):0.f;
    float e3=valid?expf(a3-nm3):0.f;
    int nc=tot-cs; if(nc>64) nc=64;
    for(int j=0;j<nc;j++){
      int s=__shfl(sj,j);
      float w0=__shfl(e0,j),w1=__shfl(e1,j),w2=__shfl(e2,j),w3=__shfl(e3,j);
      d0+=w0; d1+=w1; d2+=w2; d3+=w3;
      const float* hp=hproj+(size_t)s*NPROJ;
      float wA=(h0s==0)?w0:((h0s==1)?w1:w2);
      acc0+=wA*hp[lane];
      if(lane<32){ float wB=(h1s==2)?w2:w3; acc1+=wB*hp[64+lane]; }
    }
  }
  // epilogue: /den + bias -> ELU -> +residual -> LayerNorm
  float dA=(h0s==0)?d0:((h0s==1)?d1:d2);
  float vA=acc0/(dA+1e-16f)+bias[lane];
  vA=vA>0.f?vA:expm1f(vA);
  float tA=vA+h[(size_t)n*HIDD+lane];
  float tB=0.f;
  if(lane<32){
    float dB=(h1s==2)?d2:d3;
    float vB=acc1/(dB+1e-16f)+bias[64+lane];
    vB=vB>0.f?vB:expm1f(vB);
    tB=vB+h[(size_t)n*HIDD+64+lane];
  }
  float S1=warp_sum64(tA+tB);
  float S2=warp_sum64(tA*tA+tB*tB);
  float mean=S1*(1.f/96.f);
  float var=S2*(1.f/96.f)-mean*mean;
  float rs=rsqrtf(var+1e-5f);
  h[(size_t)n*HIDD+lane]=(tA-mean)*rs*nsc[lane]+nbi[lane];
  if(lane<32) h[(size_t)n*HIDD+64+lane]=(tB-mean)*rs*nsc[64+lane]+nbi[64+lane];
}

// ---------- prediction heads ----------
__device__ __forceinline__ void head_mlp(const float* z, float* t1, float* t2,
    const float* w1,const float* b1,const float* w2,const float* b2,
    const float* w3,const float* b3,int osz,float* outp,int lane){
  for(int j=lane;j<96;j+=64){
    float a=b1[j];
    for(int k=0;k<96;k++) a+=z[k]*w1[k*96+j];
    t1[j]=fmaxf(a,0.f);
  }
  __syncthreads();
  if(lane<48){
    float a=b2[lane];
    for(int k=0;k<96;k++) a+=t1[k]*w2[k*48+lane];
    t2[lane]=fmaxf(a,0.f);
  }
  __syncthreads();
  if(lane<osz){
    float a=b3[lane];
    for(int k=0;k<48;k++) a+=t2[k]*w3[k*osz+lane];
    outp[lane]=a;
  }
  __syncthreads();
}

__global__ void k_heads(const float* __restrict__ h, const int* __restrict__ zone,
  const float* cw1,const float* cb1,const float* cw2,const float* cb2,const float* cw3,const float* cb3,
  const float* dw1,const float* db1,const float* dw2,const float* db2,const float* dw3,const float* db3,
  const float* jw1,const float* jb1,const float* jw2,const float* jb2,const float* jw3,const float* jb3,
  float* __restrict__ out){
  __shared__ float z[96], t1[96], t2[48];
  int row=blockIdx.x, lane=threadIdx.x;
  int n=zone[row];
  for(int j=lane;j<96;j+=64) z[j]=h[(size_t)n*96+j];
  __syncthreads();
  head_mlp(z,t1,t2,cw1,cb1,cw2,cb2,cw3,cb3,2,out+row*4+0,lane);
  head_mlp(z,t1,t2,dw1,db1,dw2,db2,dw3,db3,1,out+row*4+2,lane);
  head_mlp(z,t1,t2,jw1,jb1,jw2,jb2,jw3,jb3,1,out+row*4+3,lane);
}

extern "C" void kernel_launch(void* const* d_in, const int* in_sizes, int n_in,
                              void* d_out, int out_size, void* d_ws, size_t ws_size,
                              hipStream_t stream){
  const float* x       =(const float*)d_in[0];
  const int*   eidx    =(const int*)  d_in[1];
  const float* eattr   =(const float*)d_in[2];
  const int*   zone    =(const int*)  d_in[3];
  const float* in_w1   =(const float*)d_in[4];
  const float* in_b1   =(const float*)d_in[5];
  const float* in_w2   =(const float*)d_in[6];
  const float* in_b2   =(const float*)d_in[7];
  const float* conv_w  =(const float*)d_in[8];
  const float* att_src =(const float*)d_in[9];
  const float* att_dst =(const float*)d_in[10];
  const float* lin_edge=(const float*)d_in[11];
  const float* att_edge=(const float*)d_in[12];
  const float* conv_bias=(const float*)d_in[13];
  const float* nsc     =(const float*)d_in[14];
  const float* nbi     =(const float*)d_in[15];
  float* out=(float*)d_out;

  char* p=(char*)d_ws;
  auto carve=[&](size_t bytes)->char*{ char* r=p; p+=(bytes+255)&~(size_t)255; return r; };
  float* h    =(float*)carve((size_t)NN*96*4);
  float* hproj=(float*)carve((size_t)NN*104*4);
  int*   ssrc =(int*)  carve((size_t)EE*4);
  float* sea  =(float*)carve((size_t)EE*16);
  int*   deg  =(int*)  carve((size_t)NN*4);
  int*   off  =(int*)  carve((size_t)(NN+1)*4);
  int*   cur  =(int*)  carve((size_t)NN*4);
  float* lattr=(float*)carve((size_t)NN*16);
  float* Wext =(float*)carve((size_t)4*96*104*4);
  float* Mm   =(float*)carve(64*4);
  int*   part =(int*)  carve(64*4);

  const int* srcp=eidx;
  const int* dstp=eidx+EE;

  hipMemsetAsync(deg,0,(size_t)NN*4,stream);
  hipMemsetAsync(lattr,0,(size_t)NN*16,stream);
  k_deg<<<EE/256,256,0,stream>>>(dstp,eattr,deg,lattr);
  k_scan1<<<49,256,0,stream>>>(deg,off,part);
  k_scan2<<<1,64,0,stream>>>(part,off,49);
  k_scan3<<<(NN+255)/256,256,0,stream>>>(part,off,cur);
  k_scatter<<<EE/256,256,0,stream>>>(srcp,dstp,eattr,cur,ssrc,sea);
  k_prepw<<<(4*96*104+64+255)/256,256,0,stream>>>(conv_w,att_src,att_dst,lin_edge,att_edge,Wext,Mm);

  k_mlp1<<<(NN+255)/256,256,0,stream>>>(x,in_w1,in_b1,hproj);     // hid1 staged in hproj buf
  k_gemm<96><<<(NN+63)/64,256,0,stream>>>(hproj,in_w2,in_b2,h);

  for(int l=0;l<4;l++){
    k_gemm<104><<<(NN+63)/64,256,0,stream>>>(h,Wext+(size_t)l*96*104,nullptr,hproj);
    k_agg<<<(NN+3)/4,256,0,stream>>>(hproj,h,off,ssrc,sea,lattr,Mm+l*16,
                                     conv_bias+l*96,nsc+l*96,nbi+l*96);
  }

  k_heads<<<384,64,0,stream>>>(h,zone,
    (const float*)d_in[16],(const float*)d_in[17],(const float*)d_in[18],
    (const float*)d_in[19],(const float*)d_in[20],(const float*)d_in[21],
    (const float*)d_in[22],(const float*)d_in[23],(const float*)d_in[24],
    (const float*)d_in[25],(const float*)d_in[26],(const float*)d_in[27],
    (const float*)d_in[28],(const float*)d_in[29],(const float*)d_in[30],
    (const float*)d_in[31],(const float*)d_in[32],(const float*)d_in[33],
    out);
}

// Round 2
// 812.373 us; speedup vs baseline: 1.3449x; 1.3449x over previous
//
#include <hip/hip_runtime.h>

#define NN 50000
#define EE 800000
#define HIDD 96
#define NPROJ 104

__device__ __forceinline__ float warp_max64(float v){
  #pragma unroll
  for(int m=1;m<64;m<<=1) v=fmaxf(v,__shfl_xor(v,m));
  return v;
}
__device__ __forceinline__ float warp_sum64(float v){
  #pragma unroll
  for(int m=1;m<64;m<<=1) v+=__shfl_xor(v,m);
  return v;
}

// ---------- CSR build ----------
__global__ void k_deg(const int* __restrict__ dst, int* __restrict__ deg){
  int e=blockIdx.x*blockDim.x+threadIdx.x;
  if(e>=EE) return;
  atomicAdd(&deg[dst[e]],1);
}

__global__ void k_scan1(const int* __restrict__ deg, int* __restrict__ off, int* __restrict__ part){
  __shared__ int sd[256];
  int t=threadIdx.x, b=blockIdx.x;
  int base=b*1024+t*4;
  int v0=(base+0<NN)?deg[base+0]:0;
  int v1=(base+1<NN)?deg[base+1]:0;
  int v2=(base+2<NN)?deg[base+2]:0;
  int v3=(base+3<NN)?deg[base+3]:0;
  int s=v0+v1+v2+v3;
  sd[t]=s; __syncthreads();
  for(int o=1;o<256;o<<=1){
    int x=(t>=o)?sd[t-o]:0;
    __syncthreads();
    sd[t]+=x;
    __syncthreads();
  }
  int ep=sd[t]-s;
  if(base+0<NN) off[base+0]=ep;
  if(base+1<NN) off[base+1]=ep+v0;
  if(base+2<NN) off[base+2]=ep+v0+v1;
  if(base+3<NN) off[base+3]=ep+v0+v1+v2;
  if(t==255) part[b]=sd[255];
}

__global__ void k_scan2(int* part, int* off, int nb){
  if(threadIdx.x==0&&blockIdx.x==0){
    int run=0;
    for(int i=0;i<nb;i++){ int x=part[i]; part[i]=run; run+=x; }
    off[NN]=run;
  }
}

__global__ void k_scan3(const int* __restrict__ part, int* __restrict__ off, int* __restrict__ cur){
  int i=blockIdx.x*blockDim.x+threadIdx.x;
  if(i<NN){ int v=off[i]+part[i>>10]; off[i]=v; cur[i]=v; }
}

__global__ void k_scatter(const int* __restrict__ src, const int* __restrict__ dst,
                          const float* __restrict__ eattr, int* __restrict__ cur,
                          int* __restrict__ ssrc, float* __restrict__ sea){
  int e=blockIdx.x*blockDim.x+threadIdx.x;
  if(e>=EE) return;
  int d=dst[e];
  int p=atomicAdd(&cur[d],1);
  ssrc[p]=src[e];
  *(float4*)(sea+(size_t)p*4)=*(const float4*)(eattr+(size_t)e*4);
}

// ---------- weight prep: Watt[l][k][j] (j<4: W.a_src head j ; j>=4: W.a_dst), M = We.a_edge ----------
__global__ void k_prepw(const float* __restrict__ conv_w, const float* __restrict__ a_src,
                        const float* __restrict__ a_dst, const float* __restrict__ lin_e,
                        const float* __restrict__ a_e,
                        float* __restrict__ Watt, float* __restrict__ Mm){
  int t=blockIdx.x*blockDim.x+threadIdx.x;
  const int WT=4*96*8;
  if(t<WT){
    int l=t/(96*8); int rem=t-l*(96*8); int k=rem>>3; int j=rem&7;
    int hh=j&3;
    const float* W=conv_w+(size_t)l*96*96+(size_t)k*96;
    const float* a=((j>=4)?a_dst:a_src)+l*96+hh*24;
    float v=0.f;
    #pragma unroll
    for(int c=0;c<24;c++) v+=W[hh*24+c]*a[c];
    Watt[t]=v;
  } else if(t<WT+64){
    int q=t-WT; int l=q>>4; int i=(q>>2)&3; int hh=q&3;
    const float* We=lin_e+(size_t)l*4*96+(size_t)i*96;
    const float* a=a_e+l*96+hh*24;
    float v=0.f;
    #pragma unroll
    for(int c=0;c<24;c++) v+=We[hh*24+c]*a[c];
    Mm[q]=v;  // M[l][i][h]
  }
}

// ---------- input MLP layer 1 : hid1 = relu(x @ w1 + b1) ----------
__global__ void k_mlp1(const float* __restrict__ x, const float* __restrict__ w,
                       const float* __restrict__ b, float* __restrict__ out){
  int i=blockIdx.x*blockDim.x+threadIdx.x;
  if(i>=NN) return;
  float xv[12];
  #pragma unroll
  for(int k=0;k<12;k++) xv[k]=x[(size_t)i*12+k];
  for(int j=0;j<HIDD;j++){
    float a=b[j];
    #pragma unroll
    for(int k=0;k<12;k++) a+=xv[k]*w[k*HIDD+j];
    out[(size_t)i*HIDD+j]=fmaxf(a,0.f);
  }
}

// ---------- GEMM: C[N][96] = A[N][96] @ W[96][96] (+bias), strided A/C ----------
// 64-row tile, thread = 4 rows x 6 cols. As padded to 100 (16B row align + bank spread).
__global__ __launch_bounds__(256) void k_gemm96(const float* __restrict__ A, int lda,
                                                const float* __restrict__ W,
                                                const float* __restrict__ bias,
                                                float* __restrict__ C, int ldc){
  __shared__ float As[64][100];
  __shared__ float Ws[96][96];
  int t=threadIdx.x;
  int r0=blockIdx.x*64;
  for(int i=t;i<96*96/4;i+=256) ((float4*)&Ws[0][0])[i]=((const float4*)W)[i];
  for(int i=t;i<64*24;i+=256){
    int rr=i/24, cc=(i-rr*24)*4; int g=r0+rr;
    float4 v = (g<NN)? *(const float4*)(A+(size_t)g*lda+cc) : float4{0.f,0.f,0.f,0.f};
    *(float4*)&As[rr][cc]=v;
  }
  __syncthreads();
  int cg=t&15, rg=t>>4;
  int c0=cg*6, r=rg*4;
  float acc[4][6];
  #pragma unroll
  for(int i=0;i<4;i++)
    #pragma unroll
    for(int j=0;j<6;j++) acc[i][j]=0.f;
  for(int k4=0;k4<96;k4+=4){
    float4 a0=*(float4*)&As[r  ][k4];
    float4 a1=*(float4*)&As[r+1][k4];
    float4 a2=*(float4*)&As[r+2][k4];
    float4 a3=*(float4*)&As[r+3][k4];
    #pragma unroll
    for(int kk=0;kk<4;kk++){
      float2 w01=*(float2*)&Ws[k4+kk][c0];
      float2 w23=*(float2*)&Ws[k4+kk][c0+2];
      float2 w45=*(float2*)&Ws[k4+kk][c0+4];
      float wv[6]={w01.x,w01.y,w23.x,w23.y,w45.x,w45.y};
      float av0=((float*)&a0)[kk],av1=((float*)&a1)[kk],av2=((float*)&a2)[kk],av3=((float*)&a3)[kk];
      #pragma unroll
      for(int j=0;j<6;j++){
        acc[0][j]+=av0*wv[j];
        acc[1][j]+=av1*wv[j];
        acc[2][j]+=av2*wv[j];
        acc[3][j]+=av3*wv[j];
      }
    }
  }
  #pragma unroll
  for(int i=0;i<4;i++){
    int g=r0+r+i;
    if(g<NN){
      #pragma unroll
      for(int j=0;j<6;j++) C[(size_t)g*ldc+c0+j]=acc[i][j]+(bias?bias[c0+j]:0.f);
    }
  }
}

// ---------- attention logit columns: hproj[n][96..104) = h[n][:] @ W8[96][8] ----------
__global__ __launch_bounds__(256) void k_att8(const float* __restrict__ h, const float* __restrict__ W8,
                                              float* __restrict__ hproj){
  __shared__ float ws[96*8];
  int t=threadIdx.x;
  for(int i=t;i<768;i+=256) ws[i]=W8[i];
  __syncthreads();
  int n=blockIdx.x*256+t;
  if(n>=NN) return;
  float acc[8];
  #pragma unroll
  for(int j=0;j<8;j++) acc[j]=0.f;
  for(int k4=0;k4<24;k4++){
    float4 v=*(const float4*)(h+(size_t)n*96+k4*4);
    #pragma unroll
    for(int kk=0;kk<4;kk++){
      float a=((float*)&v)[kk];
      #pragma unroll
      for(int j=0;j<8;j++) acc[j]+=a*ws[(k4*4+kk)*8+j];
    }
  }
  #pragma unroll
  for(int j=0;j<8;j++) hproj[(size_t)n*NPROJ+96+j]=acc[j];
}

// ---------- fused GAT aggregation + self-loop + bias + ELU + residual + LayerNorm ----------
// one 64-lane wave per node; hproj[n] = [96 proj | a_src(4) | a_dst(4)]
__global__ __launch_bounds__(256) void k_agg(const float* __restrict__ hproj, float* __restrict__ h,
    const int* __restrict__ off, const int* __restrict__ ssrc, const float* __restrict__ sea,
    const float* __restrict__ Mm,
    const float* __restrict__ bias, const float* __restrict__ nsc, const float* __restrict__ nbi){
  int wid=threadIdx.x>>6, lane=threadIdx.x&63;
  int n=blockIdx.x*4+wid;
  if(n>=NN) return;
  float M[16];
  #pragma unroll
  for(int i=0;i<16;i++) M[i]=Mm[i];
  const float4 ad=*(const float4*)(hproj+(size_t)n*NPROJ+100);
  int b0=off[n]; int deg=off[n+1]-b0;
  float invdeg=1.f/(float)(deg>0?deg:1);
  float m0=-INFINITY,m1=-INFINITY,m2=-INFINITY,m3=-INFINITY;
  float d0=0.f,d1=0.f,d2=0.f,d3=0.f;
  float acc0=0.f, acc1=0.f;
  float sx=0.f,sy=0.f,sz=0.f,sw=0.f;   // edge-attr sums for self-loop mean
  int h0s=lane/24;        // head of dim 'lane' (0..2)
  int h1s=(64+lane)/24;   // head of dim 64+lane (2 or 3)
  for(int cs=0;cs<deg;cs+=64){
    int idx=cs+lane;
    bool valid=idx<deg;
    float a0=-INFINITY,a1=-INFINITY,a2=-INFINITY,a3=-INFINITY;
    int sj=n;
    if(valid){
      int ei=b0+idx;
      sj=ssrc[ei];
      float4 ea=*(const float4*)(sea+(size_t)ei*4);
      sx+=ea.x; sy+=ea.y; sz+=ea.z; sw+=ea.w;
      const float4 as=*(const float4*)(hproj+(size_t)sj*NPROJ+96);
      a0=as.x+ad.x+ea.x*M[0]+ea.y*M[4]+ea.z*M[8] +ea.w*M[12];
      a1=as.y+ad.y+ea.x*M[1]+ea.y*M[5]+ea.z*M[9] +ea.w*M[13];
      a2=as.z+ad.z+ea.x*M[2]+ea.y*M[6]+ea.z*M[10]+ea.w*M[14];
      a3=as.w+ad.w+ea.x*M[3]+ea.y*M[7]+ea.z*M[11]+ea.w*M[15];
      a0=a0>0.f?a0:0.2f*a0; a1=a1>0.f?a1:0.2f*a1;
      a2=a2>0.f?a2:0.2f*a2; a3=a3>0.f?a3:0.2f*a3;
    }
    float c0=warp_max64(a0),c1=warp_max64(a1),c2=warp_max64(a2),c3=warp_max64(a3);
    float nm0=fmaxf(m0,c0),nm1=fmaxf(m1,c1),nm2=fmaxf(m2,c2),nm3=fmaxf(m3,c3);
    float s0=expf(m0-nm0),s1=expf(m1-nm1),s2=expf(m2-nm2),s3=expf(m3-nm3);
    d0*=s0; d1*=s1; d2*=s2; d3*=s3;
    float scA=(h0s==0)?s0:((h0s==1)?s1:s2);
    acc0*=scA;
    float scB=(h1s==2)?s2:s3;
    acc1*=scB;
    m0=nm0;m1=nm1;m2=nm2;m3=nm3;
    float e0=valid?expf(a0-nm0):0.f;
    float e1=valid?expf(a1-nm1):0.f;
    float e2=valid?expf(a2-nm2):0.f;
    float e3=valid?expf(a3-nm3):0.f;
    int nc=deg-cs; if(nc>64) nc=64;
    for(int j=0;j<nc;j++){
      int s=__shfl(sj,j);
      float w0=__shfl(e0,j),w1=__shfl(e1,j),w2=__shfl(e2,j),w3=__shfl(e3,j);
      d0+=w0; d1+=w1; d2+=w2; d3+=w3;
      const float* hp=hproj+(size_t)s*NPROJ;
      float wA=(h0s==0)?w0:((h0s==1)?w1:w2);
      acc0+=wA*hp[lane];
      if(lane<32){ float wB=(h1s==2)?w2:w3; acc1+=wB*hp[64+lane]; }
    }
  }
  // ---- self-loop with mean edge-attr ----
  sx=warp_sum64(sx); sy=warp_sum64(sy); sz=warp_sum64(sz); sw=warp_sum64(sw);
  float lx=sx*invdeg, ly=sy*invdeg, lz=sz*invdeg, lw=sw*invdeg;
  const float4 aself=*(const float4*)(hproj+(size_t)n*NPROJ+96);
  float b0a=aself.x+ad.x+lx*M[0]+ly*M[4]+lz*M[8] +lw*M[12];
  float b1a=aself.y+ad.y+lx*M[1]+ly*M[5]+lz*M[9] +lw*M[13];
  float b2a=aself.z+ad.z+lx*M[2]+ly*M[6]+lz*M[10]+lw*M[14];
  float b3a=aself.w+ad.w+lx*M[3]+ly*M[7]+lz*M[11]+lw*M[15];
  b0a=b0a>0.f?b0a:0.2f*b0a; b1a=b1a>0.f?b1a:0.2f*b1a;
  b2a=b2a>0.f?b2a:0.2f*b2a; b3a=b3a>0.f?b3a:0.2f*b3a;
  {
    float nm0=fmaxf(m0,b0a),nm1=fmaxf(m1,b1a),nm2=fmaxf(m2,b2a),nm3=fmaxf(m3,b3a);
    float s0=expf(m0-nm0),s1=expf(m1-nm1),s2=expf(m2-nm2),s3=expf(m3-nm3);
    float e0=expf(b0a-nm0),e1=expf(b1a-nm1),e2=expf(b2a-nm2),e3=expf(b3a-nm3);
    d0=d0*s0+e0; d1=d1*s1+e1; d2=d2*s2+e2; d3=d3*s3+e3;
    float scA=(h0s==0)?s0:((h0s==1)?s1:s2);
    float eA =(h0s==0)?e0:((h0s==1)?e1:e2);
    acc0=acc0*scA+eA*hproj[(size_t)n*NPROJ+lane];
    if(lane<32){
      float scB=(h1s==2)?s2:s3;
      float eB =(h1s==2)?e2:e3;
      acc1=acc1*scB+eB*hproj[(size_t)n*NPROJ+64+lane];
    }
  }
  // epilogue: /den + bias -> ELU -> +residual -> LayerNorm
  float dA=(h0s==0)?d0:((h0s==1)?d1:d2);
  float vA=acc0/(dA+1e-16f)+bias[lane];
  vA=vA>0.f?vA:expm1f(vA);
  float tA=vA+h[(size_t)n*HIDD+lane];
  float tB=0.f;
  if(lane<32){
    float dB=(h1s==2)?d2:d3;
    float vB=acc1/(dB+1e-16f)+bias[64+lane];
    vB=vB>0.f?vB:expm1f(vB);
    tB=vB+h[(size_t)n*HIDD+64+lane];
  }
  float S1=warp_sum64(tA+tB);
  float S2=warp_sum64(tA*tA+tB*tB);
  float mean=S1*(1.f/96.f);
  float var=S2*(1.f/96.f)-mean*mean;
  float rs=rsqrtf(var+1e-5f);
  h[(size_t)n*HIDD+lane]=(tA-mean)*rs*nsc[lane]+nbi[lane];
  if(lane<32) h[(size_t)n*HIDD+64+lane]=(tB-mean)*rs*nsc[64+lane]+nbi[64+lane];
}

// ---------- prediction heads ----------
__device__ __forceinline__ void head_mlp(const float* z, float* t1, float* t2,
    const float* w1,const float* b1,const float* w2,const float* b2,
    const float* w3,const float* b3,int osz,float* outp,int lane){
  for(int j=lane;j<96;j+=64){
    float a=b1[j];
    for(int k=0;k<96;k++) a+=z[k]*w1[k*96+j];
    t1[j]=fmaxf(a,0.f);
  }
  __syncthreads();
  if(lane<48){
    float a=b2[lane];
    for(int k=0;k<96;k++) a+=t1[k]*w2[k*48+lane];
    t2[lane]=fmaxf(a,0.f);
  }
  __syncthreads();
  if(lane<osz){
    float a=b3[lane];
    for(int k=0;k<48;k++) a+=t2[k]*w3[k*osz+lane];
    outp[lane]=a;
  }
  __syncthreads();
}

__global__ void k_heads(const float* __restrict__ h, const int* __restrict__ zone,
  const float* cw1,const float* cb1,const float* cw2,const float* cb2,const float* cw3,const float* cb3,
  const float* dw1,const float* db1,const float* dw2,const float* db2,const float* dw3,const float* db3,
  const float* jw1,const float* jb1,const float* jw2,const float* jb2,const float* jw3,const float* jb3,
  float* __restrict__ out){
  __shared__ float z[96], t1[96], t2[48];
  int row=blockIdx.x, lane=threadIdx.x;
  int n=zone[row];
  for(int j=lane;j<96;j+=64) z[j]=h[(size_t)n*96+j];
  __syncthreads();
  head_mlp(z,t1,t2,cw1,cb1,cw2,cb2,cw3,cb3,2,out+row*4+0,lane);
  head_mlp(z,t1,t2,dw1,db1,dw2,db2,dw3,db3,1,out+row*4+2,lane);
  head_mlp(z,t1,t2,jw1,jb1,jw2,jb2,jw3,jb3,1,out+row*4+3,lane);
}

extern "C" void kernel_launch(void* const* d_in, const int* in_sizes, int n_in,
                              void* d_out, int out_size, void* d_ws, size_t ws_size,
                              hipStream_t stream){
  const float* x       =(const float*)d_in[0];
  const int*   eidx    =(const int*)  d_in[1];
  const float* eattr   =(const float*)d_in[2];
  const int*   zone    =(const int*)  d_in[3];
  const float* in_w1   =(const float*)d_in[4];
  const float* in_b1   =(const float*)d_in[5];
  const float* in_w2   =(const float*)d_in[6];
  const float* in_b2   =(const float*)d_in[7];
  const float* conv_w  =(const float*)d_in[8];
  const float* att_src =(const float*)d_in[9];
  const float* att_dst =(const float*)d_in[10];
  const float* lin_edge=(const float*)d_in[11];
  const float* att_edge=(const float*)d_in[12];
  const float* conv_bias=(const float*)d_in[13];
  const float* nsc     =(const float*)d_in[14];
  const float* nbi     =(const float*)d_in[15];
  float* out=(float*)d_out;

  char* p=(char*)d_ws;
  auto carve=[&](size_t bytes)->char*{ char* r=p; p+=(bytes+255)&~(size_t)255; return r; };
  float* h    =(float*)carve((size_t)NN*96*4);
  float* hproj=(float*)carve((size_t)NN*104*4);
  int*   ssrc =(int*)  carve((size_t)EE*4);
  float* sea  =(float*)carve((size_t)EE*16);
  int*   deg  =(int*)  carve((size_t)NN*4);
  int*   off  =(int*)  carve((size_t)(NN+1)*4);
  int*   cur  =(int*)  carve((size_t)NN*4);
  float* Watt =(float*)carve((size_t)4*96*8*4);
  float* Mm   =(float*)carve(64*4);
  int*   part =(int*)  carve(64*4);

  const int* srcp=eidx;
  const int* dstp=eidx+EE;

  hipMemsetAsync(deg,0,(size_t)NN*4,stream);
  k_deg<<<EE/256,256,0,stream>>>(dstp,deg);
  k_scan1<<<49,256,0,stream>>>(deg,off,part);
  k_scan2<<<1,64,0,stream>>>(part,off,49);
  k_scan3<<<(NN+255)/256,256,0,stream>>>(part,off,cur);
  k_scatter<<<EE/256,256,0,stream>>>(srcp,dstp,eattr,cur,ssrc,sea);
  k_prepw<<<(4*96*8+64+255)/256,256,0,stream>>>(conv_w,att_src,att_dst,lin_edge,att_edge,Watt,Mm);

  k_mlp1<<<(NN+255)/256,256,0,stream>>>(x,in_w1,in_b1,hproj);     // hid1 staged in hproj buf (stride 96)
  k_gemm96<<<(NN+63)/64,256,0,stream>>>(hproj,96,in_w2,in_b2,h,96);

  for(int l=0;l<4;l++){
    k_gemm96<<<(NN+63)/64,256,0,stream>>>(h,96,conv_w+(size_t)l*96*96,nullptr,hproj,NPROJ);
    k_att8<<<(NN+255)/256,256,0,stream>>>(h,Watt+(size_t)l*96*8,hproj);
    k_agg<<<(NN+3)/4,256,0,stream>>>(hproj,h,off,ssrc,sea,Mm+l*16,
                                     conv_bias+l*96,nsc+l*96,nbi+l*96);
  }

  k_heads<<<384,64,0,stream>>>(h,zone,
    (const float*)d_in[16],(const float*)d_in[17],(const float*)d_in[18],
    (const float*)d_in[19],(const float*)d_in[20],(const float*)d_in[21],
    (const float*)d_in[22],(const float*)d_in[23],(const float*)d_in[24],
    (const float*)d_in[25],(const float*)d_in[26],(const float*)d_in[27],
    (const float*)d_in[28],(const float*)d_in[29],(const float*)d_in[30],
    (const float*)d_in[31],(const float*)d_in[32],(const float*)d_in[33],
    out);
}

// Round 3
// 695.822 us; speedup vs baseline: 1.5701x; 1.1675x over previous
//
#include <hip/hip_runtime.h>

#define NN 50000
#define EE 800000
#define HIDD 96
#define NPROJ 104
#define NZ 384   // BATCH*NUM_ZONES

__device__ __forceinline__ float warp_max64(float v){
  #pragma unroll
  for(int m=1;m<64;m<<=1) v=fmaxf(v,__shfl_xor(v,m));
  return v;
}
__device__ __forceinline__ float warp_sum64(float v){
  #pragma unroll
  for(int m=1;m<64;m<<=1) v+=__shfl_xor(v,m);
  return v;
}

// ---------- CSR build ----------
__global__ void k_deg(const int* __restrict__ dst, int* __restrict__ deg){
  int e=blockIdx.x*blockDim.x+threadIdx.x;
  if(e>=EE) return;
  atomicAdd(&deg[dst[e]],1);
}

__global__ void k_scan1(const int* __restrict__ deg, int* __restrict__ off, int* __restrict__ part){
  __shared__ int sd[256];
  int t=threadIdx.x, b=blockIdx.x;
  int base=b*1024+t*4;
  int v0=(base+0<NN)?deg[base+0]:0;
  int v1=(base+1<NN)?deg[base+1]:0;
  int v2=(base+2<NN)?deg[base+2]:0;
  int v3=(base+3<NN)?deg[base+3]:0;
  int s=v0+v1+v2+v3;
  sd[t]=s; __syncthreads();
  for(int o=1;o<256;o<<=1){
    int x=(t>=o)?sd[t-o]:0;
    __syncthreads();
    sd[t]+=x;
    __syncthreads();
  }
  int ep=sd[t]-s;
  if(base+0<NN) off[base+0]=ep;
  if(base+1<NN) off[base+1]=ep+v0;
  if(base+2<NN) off[base+2]=ep+v0+v1;
  if(base+3<NN) off[base+3]=ep+v0+v1+v2;
  if(t==255) part[b]=sd[255];
}

__global__ void k_scan2(int* part, int* off, int nb){
  if(threadIdx.x==0&&blockIdx.x==0){
    int run=0;
    for(int i=0;i<nb;i++){ int x=part[i]; part[i]=run; run+=x; }
    off[NN]=run;
  }
}

__global__ void k_scan3(const int* __restrict__ part, int* __restrict__ off, int* __restrict__ cur){
  int i=blockIdx.x*blockDim.x+threadIdx.x;
  if(i<NN){ int v=off[i]+part[i>>10]; off[i]=v; cur[i]=v; }
}

__global__ void k_scatter(const int* __restrict__ src, const int* __restrict__ dst,
                          const float* __restrict__ eattr, int* __restrict__ cur,
                          int* __restrict__ ssrc, float* __restrict__ sea){
  int e=blockIdx.x*blockDim.x+threadIdx.x;
  if(e>=EE) return;
  int d=dst[e];
  int p=atomicAdd(&cur[d],1);
  ssrc[p]=src[e];
  *(float4*)(sea+(size_t)p*4)=*(const float4*)(eattr+(size_t)e*4);
}

// ---------- weight prep: Watt[l][k][j] (j<4: W.a_src head j ; j>=4: W.a_dst), M = We.a_edge ----------
__global__ void k_prepw(const float* __restrict__ conv_w, const float* __restrict__ a_src,
                        const float* __restrict__ a_dst, const float* __restrict__ lin_e,
                        const float* __restrict__ a_e,
                        float* __restrict__ Watt, float* __restrict__ Mm){
  int t=blockIdx.x*blockDim.x+threadIdx.x;
  const int WT=4*96*8;
  if(t<WT){
    int l=t/(96*8); int rem=t-l*(96*8); int k=rem>>3; int j=rem&7;
    int hh=j&3;
    const float* W=conv_w+(size_t)l*96*96+(size_t)k*96;
    const float* a=((j>=4)?a_dst:a_src)+l*96+hh*24;
    float v=0.f;
    #pragma unroll
    for(int c=0;c<24;c++) v+=W[hh*24+c]*a[c];
    Watt[t]=v;
  } else if(t<WT+64){
    int q=t-WT; int l=q>>4; int i=(q>>2)&3; int hh=q&3;
    const float* We=lin_e+(size_t)l*4*96+(size_t)i*96;
    const float* a=a_e+l*96+hh*24;
    float v=0.f;
    #pragma unroll
    for(int c=0;c<24;c++) v+=We[hh*24+c]*a[c];
    Mm[q]=v;  // M[l][i][h]
  }
}

// ---------- input MLP layer 1 : hid1 = relu(x @ w1 + b1) ----------
__global__ void k_mlp1(const float* __restrict__ x, const float* __restrict__ w,
                       const float* __restrict__ b, float* __restrict__ out){
  int i=blockIdx.x*blockDim.x+threadIdx.x;
  if(i>=NN) return;
  float xv[12];
  #pragma unroll
  for(int k=0;k<12;k++) xv[k]=x[(size_t)i*12+k];
  for(int j=0;j<HIDD;j++){
    float a=b[j];
    #pragma unroll
    for(int k=0;k<12;k++) a+=xv[k]*w[k*HIDD+j];
    out[(size_t)i*HIDD+j]=fmaxf(a,0.f);
  }
}

// ---------- GEMM: C[N][96] = A[N][96] @ W[96][96] (+bias), strided A/C ----------
__global__ __launch_bounds__(256) void k_gemm96(const float* __restrict__ A, int lda,
                                                const float* __restrict__ W,
                                                const float* __restrict__ bias,
                                                float* __restrict__ C, int ldc){
  __shared__ float As[64][100];
  __shared__ float Ws[96][96];
  int t=threadIdx.x;
  int r0=blockIdx.x*64;
  for(int i=t;i<96*96/4;i+=256) ((float4*)&Ws[0][0])[i]=((const float4*)W)[i];
  for(int i=t;i<64*24;i+=256){
    int rr=i/24, cc=(i-rr*24)*4; int g=r0+rr;
    float4 v = (g<NN)? *(const float4*)(A+(size_t)g*lda+cc) : float4{0.f,0.f,0.f,0.f};
    *(float4*)&As[rr][cc]=v;
  }
  __syncthreads();
  int cg=t&15, rg=t>>4;
  int c0=cg*6, r=rg*4;
  float acc[4][6];
  #pragma unroll
  for(int i=0;i<4;i++)
    #pragma unroll
    for(int j=0;j<6;j++) acc[i][j]=0.f;
  for(int k4=0;k4<96;k4+=4){
    float4 a0=*(float4*)&As[r  ][k4];
    float4 a1=*(float4*)&As[r+1][k4];
    float4 a2=*(float4*)&As[r+2][k4];
    float4 a3=*(float4*)&As[r+3][k4];
    #pragma unroll
    for(int kk=0;kk<4;kk++){
      float2 w01=*(float2*)&Ws[k4+kk][c0];
      float2 w23=*(float2*)&Ws[k4+kk][c0+2];
      float2 w45=*(float2*)&Ws[k4+kk][c0+4];
      float wv[6]={w01.x,w01.y,w23.x,w23.y,w45.x,w45.y};
      float av0=((float*)&a0)[kk],av1=((float*)&a1)[kk],av2=((float*)&a2)[kk],av3=((float*)&a3)[kk];
      #pragma unroll
      for(int j=0;j<6;j++){
        acc[0][j]+=av0*wv[j];
        acc[1][j]+=av1*wv[j];
        acc[2][j]+=av2*wv[j];
        acc[3][j]+=av3*wv[j];
      }
    }
  }
  #pragma unroll
  for(int i=0;i<4;i++){
    int g=r0+r+i;
    if(g<NN){
      #pragma unroll
      for(int j=0;j<6;j++) C[(size_t)g*ldc+c0+j]=acc[i][j]+(bias?bias[c0+j]:0.f);
    }
  }
}

// ---------- attention logit columns: hproj[n][96..104) = h[n][:] @ W8[96][8] ----------
__global__ __launch_bounds__(256) void k_att8(const float* __restrict__ h, const float* __restrict__ W8,
                                              float* __restrict__ hproj){
  __shared__ float ws[96*8];
  int t=threadIdx.x;
  for(int i=t;i<768;i+=256) ws[i]=W8[i];
  __syncthreads();
  int n=blockIdx.x*256+t;
  if(n>=NN) return;
  float acc[8];
  #pragma unroll
  for(int j=0;j<8;j++) acc[j]=0.f;
  for(int k4=0;k4<24;k4++){
    float4 v=*(const float4*)(h+(size_t)n*96+k4*4);
    #pragma unroll
    for(int kk=0;kk<4;kk++){
      float a=((float*)&v)[kk];
      #pragma unroll
      for(int j=0;j<8;j++) acc[j]+=a*ws[(k4*4+kk)*8+j];
    }
  }
  #pragma unroll
  for(int j=0;j<8;j++) hproj[(size_t)n*NPROJ+96+j]=acc[j];
}

// ---------- fused GAT aggregation + self-loop + bias + ELU + residual + LayerNorm ----------
__global__ __launch_bounds__(256) void k_agg(const float* __restrict__ hproj, float* __restrict__ h,
    const int* __restrict__ off, const int* __restrict__ ssrc, const float* __restrict__ sea,
    const float* __restrict__ Mm,
    const float* __restrict__ bias, const float* __restrict__ nsc, const float* __restrict__ nbi){
  int wid=threadIdx.x>>6, lane=threadIdx.x&63;
  int n=blockIdx.x*4+wid;
  if(n>=NN) return;
  float M[16];
  #pragma unroll
  for(int i=0;i<16;i++) M[i]=Mm[i];
  const float4 ad=*(const float4*)(hproj+(size_t)n*NPROJ+100);
  int b0=off[n]; int deg=off[n+1]-b0;
  float invdeg=1.f/(float)(deg>0?deg:1);
  float m0=-INFINITY,m1=-INFINITY,m2=-INFINITY,m3=-INFINITY;
  float d0=0.f,d1=0.f,d2=0.f,d3=0.f;
  float acc0=0.f, acc1=0.f;
  float sx=0.f,sy=0.f,sz=0.f,sw=0.f;
  int h0s=lane/24;
  int h1s=(64+lane)/24;
  for(int cs=0;cs<deg;cs+=64){
    int idx=cs+lane;
    bool valid=idx<deg;
    float a0=-INFINITY,a1=-INFINITY,a2=-INFINITY,a3=-INFINITY;
    int sj=n;
    if(valid){
      int ei=b0+idx;
      sj=ssrc[ei];
      float4 ea=*(const float4*)(sea+(size_t)ei*4);
      sx+=ea.x; sy+=ea.y; sz+=ea.z; sw+=ea.w;
      const float4 as=*(const float4*)(hproj+(size_t)sj*NPROJ+96);
      a0=as.x+ad.x+ea.x*M[0]+ea.y*M[4]+ea.z*M[8] +ea.w*M[12];
      a1=as.y+ad.y+ea.x*M[1]+ea.y*M[5]+ea.z*M[9] +ea.w*M[13];
      a2=as.z+ad.z+ea.x*M[2]+ea.y*M[6]+ea.z*M[10]+ea.w*M[14];
      a3=as.w+ad.w+ea.x*M[3]+ea.y*M[7]+ea.z*M[11]+ea.w*M[15];
      a0=a0>0.f?a0:0.2f*a0; a1=a1>0.f?a1:0.2f*a1;
      a2=a2>0.f?a2:0.2f*a2; a3=a3>0.f?a3:0.2f*a3;
    }
    float c0=warp_max64(a0),c1=warp_max64(a1),c2=warp_max64(a2),c3=warp_max64(a3);
    float nm0=fmaxf(m0,c0),nm1=fmaxf(m1,c1),nm2=fmaxf(m2,c2),nm3=fmaxf(m3,c3);
    float s0=expf(m0-nm0),s1=expf(m1-nm1),s2=expf(m2-nm2),s3=expf(m3-nm3);
    d0*=s0; d1*=s1; d2*=s2; d3*=s3;
    float scA=(h0s==0)?s0:((h0s==1)?s1:s2);
    acc0*=scA;
    float scB=(h1s==2)?s2:s3;
    acc1*=scB;
    m0=nm0;m1=nm1;m2=nm2;m3=nm3;
    float e0=valid?expf(a0-nm0):0.f;
    float e1=valid?expf(a1-nm1):0.f;
    float e2=valid?expf(a2-nm2):0.f;
    float e3=valid?expf(a3-nm3):0.f;
    int nc=deg-cs; if(nc>64) nc=64;
    for(int j=0;j<nc;j++){
      int s=__shfl(sj,j);
      float w0=__shfl(e0,j),w1=__shfl(e1,j),w2=__shfl(e2,j),w3=__shfl(e3,j);
      d0+=w0; d1+=w1; d2+=w2; d3+=w3;
      const float* hp=hproj+(size_t)s*NPROJ;
      float wA=(h0s==0)?w0:((h0s==1)?w1:w2);
      acc0+=wA*hp[lane];
      if(lane<32){ float wB=(h1s==2)?w2:w3; acc1+=wB*hp[64+lane]; }
    }
  }
  sx=warp_sum64(sx); sy=warp_sum64(sy); sz=warp_sum64(sz); sw=warp_sum64(sw);
  float lx=sx*invdeg, ly=sy*invdeg, lz=sz*invdeg, lw=sw*invdeg;
  const float4 aself=*(const float4*)(hproj+(size_t)n*NPROJ+96);
  float b0a=aself.x+ad.x+lx*M[0]+ly*M[4]+lz*M[8] +lw*M[12];
  float b1a=aself.y+ad.y+lx*M[1]+ly*M[5]+lz*M[9] +lw*M[13];
  float b2a=aself.z+ad.z+lx*M[2]+ly*M[6]+lz*M[10]+lw*M[14];
  float b3a=aself.w+ad.w+lx*M[3]+ly*M[7]+lz*M[11]+lw*M[15];
  b0a=b0a>0.f?b0a:0.2f*b0a; b1a=b1a>0.f?b1a:0.2f*b1a;
  b2a=b2a>0.f?b2a:0.2f*b2a; b3a=b3a>0.f?b3a:0.2f*b3a;
  {
    float nm0=fmaxf(m0,b0a),nm1=fmaxf(m1,b1a),nm2=fmaxf(m2,b2a),nm3=fmaxf(m3,b3a);
    float s0=expf(m0-nm0),s1=expf(m1-nm1),s2=expf(m2-nm2),s3=expf(m3-nm3);
    float e0=expf(b0a-nm0),e1=expf(b1a-nm1),e2=expf(b2a-nm2),e3=expf(b3a-nm3);
    d0=d0*s0+e0; d1=d1*s1+e1; d2=d2*s2+e2; d3=d3*s3+e3;
    float scA=(h0s==0)?s0:((h0s==1)?s1:s2);
    float eA =(h0s==0)?e0:((h0s==1)?e1:e2);
    acc0=acc0*scA+eA*hproj[(size_t)n*NPROJ+lane];
    if(lane<32){
      float scB=(h1s==2)?s2:s3;
      float eB =(h1s==2)?e2:e3;
      acc1=acc1*scB+eB*hproj[(size_t)n*NPROJ+64+lane];
    }
  }
  float dA=(h0s==0)?d0:((h0s==1)?d1:d2);
  float vA=acc0/(dA+1e-16f)+bias[lane];
  vA=vA>0.f?vA:expm1f(vA);
  float tA=vA+h[(size_t)n*HIDD+lane];
  float tB=0.f;
  if(lane<32){
    float dB=(h1s==2)?d2:d3;
    float vB=acc1/(dB+1e-16f)+bias[64+lane];
    vB=vB>0.f?vB:expm1f(vB);
    tB=vB+h[(size_t)n*HIDD+64+lane];
  }
  float S1=warp_sum64(tA+tB);
  float S2=warp_sum64(tA*tA+tB*tB);
  float mean=S1*(1.f/96.f);
  float var=S2*(1.f/96.f)-mean*mean;
  float rs=rsqrtf(var+1e-5f);
  h[(size_t)n*HIDD+lane]=(tA-mean)*rs*nsc[lane]+nbi[lane];
  if(lane<32) h[(size_t)n*HIDD+64+lane]=(tB-mean)*rs*nsc[64+lane]+nbi[64+lane];
}

// ---------- prediction heads: wide one-thread-per-output stages ----------
// t1[hd][row][j] = relu(b1[j] + sum_k h[zone[row]][k] * w1[k*96+j])
__global__ __launch_bounds__(256) void k_hd1(const float* __restrict__ h, const int* __restrict__ zone,
    const float* __restrict__ cw1,const float* __restrict__ cb1,
    const float* __restrict__ dw1,const float* __restrict__ db1,
    const float* __restrict__ jw1,const float* __restrict__ jb1,
    float* __restrict__ t1){
  int idx=blockIdx.x*256+threadIdx.x;
  if(idx>=3*NZ*96) return;
  int hd=idx/(NZ*96); int rem=idx-hd*(NZ*96); int row=rem/96; int j=rem-row*96;
  const float* w1=(hd==0)?cw1:((hd==1)?dw1:jw1);
  const float* b1=(hd==0)?cb1:((hd==1)?db1:jb1);
  int n=zone[row];
  const float* hr=h+(size_t)n*96;
  float acc=b1[j];
  #pragma unroll
  for(int k4=0;k4<24;k4++){
    float4 hv=*(const float4*)(hr+k4*4);
    acc+=hv.x*w1[(k4*4+0)*96+j];
    acc+=hv.y*w1[(k4*4+1)*96+j];
    acc+=hv.z*w1[(k4*4+2)*96+j];
    acc+=hv.w*w1[(k4*4+3)*96+j];
  }
  t1[idx]=fmaxf(acc,0.f);
}

// t2[hd][row][c] = relu(b2[c] + sum_k t1[hd][row][k] * w2[k*48+c])
__global__ __launch_bounds__(256) void k_hd2(const float* __restrict__ t1,
    const float* __restrict__ cw2,const float* __restrict__ cb2,
    const float* __restrict__ dw2,const float* __restrict__ db2,
    const float* __restrict__ jw2,const float* __restrict__ jb2,
    float* __restrict__ t2){
  int idx=blockIdx.x*256+threadIdx.x;
  if(idx>=3*NZ*48) return;
  int hd=idx/(NZ*48); int rem=idx-hd*(NZ*48); int row=rem/48; int c=rem-row*48;
  const float* w2=(hd==0)?cw2:((hd==1)?dw2:jw2);
  const float* b2=(hd==0)?cb2:((hd==1)?db2:jb2);
  const float* t1r=t1+(size_t)hd*NZ*96+(size_t)row*96;
  float acc=b2[c];
  #pragma unroll
  for(int k4=0;k4<24;k4++){
    float4 tv=*(const float4*)(t1r+k4*4);
    acc+=tv.x*w2[(k4*4+0)*48+c];
    acc+=tv.y*w2[(k4*4+1)*48+c];
    acc+=tv.z*w2[(k4*4+2)*48+c];
    acc+=tv.w*w2[(k4*4+3)*48+c];
  }
  t2[idx]=fmaxf(acc,0.f);
}

// out[row][o]: o in {0,1}->cong col o; o==2->delay; o==3->jit
__global__ __launch_bounds__(256) void k_hd3(const float* __restrict__ t2,
    const float* __restrict__ cw3,const float* __restrict__ cb3,
    const float* __restrict__ dw3,const float* __restrict__ db3,
    const float* __restrict__ jw3,const float* __restrict__ jb3,
    float* __restrict__ out){
  int idx=blockIdx.x*256+threadIdx.x;
  if(idx>=NZ*4) return;
  int row=idx>>2, o=idx&3;
  int hd=(o<2)?0:((o==2)?1:2);
  int c=(o<2)?o:0;
  int osz=(hd==0)?2:1;
  const float* w3=(hd==0)?cw3:((hd==1)?dw3:jw3);
  const float* b3=(hd==0)?cb3:((hd==1)?db3:jb3);
  const float* t2r=t2+(size_t)hd*NZ*48+(size_t)row*48;
  float acc=b3[c];
  #pragma unroll
  for(int k=0;k<48;k++) acc+=t2r[k]*w3[k*osz+c];
  out[idx]=acc;
}

extern "C" void kernel_launch(void* const* d_in, const int* in_sizes, int n_in,
                              void* d_out, int out_size, void* d_ws, size_t ws_size,
                              hipStream_t stream){
  const float* x       =(const float*)d_in[0];
  const int*   eidx    =(const int*)  d_in[1];
  const float* eattr   =(const float*)d_in[2];
  const int*   zone    =(const int*)  d_in[3];
  const float* in_w1   =(const float*)d_in[4];
  const float* in_b1   =(const float*)d_in[5];
  const float* in_w2   =(const float*)d_in[6];
  const float* in_b2   =(const float*)d_in[7];
  const float* conv_w  =(const float*)d_in[8];
  const float* att_src =(const float*)d_in[9];
  const float* att_dst =(const float*)d_in[10];
  const float* lin_edge=(const float*)d_in[11];
  const float* att_edge=(const float*)d_in[12];
  const float* conv_bias=(const float*)d_in[13];
  const float* nsc     =(const float*)d_in[14];
  const float* nbi     =(const float*)d_in[15];
  float* out=(float*)d_out;

  char* p=(char*)d_ws;
  auto carve=[&](size_t bytes)->char*{ char* r=p; p+=(bytes+255)&~(size_t)255; return r; };
  float* h    =(float*)carve((size_t)NN*96*4);
  float* hproj=(float*)carve((size_t)NN*104*4);
  int*   ssrc =(int*)  carve((size_t)EE*4);
  float* sea  =(float*)carve((size_t)EE*16);
  int*   deg  =(int*)  carve((size_t)NN*4);
  int*   off  =(int*)  carve((size_t)(NN+1)*4);
  int*   cur  =(int*)  carve((size_t)NN*4);
  float* Watt =(float*)carve((size_t)4*96*8*4);
  float* Mm   =(float*)carve(64*4);
  int*   part =(int*)  carve(64*4);
  float* t1b  =(float*)carve((size_t)3*NZ*96*4);
  float* t2b  =(float*)carve((size_t)3*NZ*48*4);

  const int* srcp=eidx;
  const int* dstp=eidx+EE;

  hipMemsetAsync(deg,0,(size_t)NN*4,stream);
  k_deg<<<EE/256,256,0,stream>>>(dstp,deg);
  k_scan1<<<49,256,0,stream>>>(deg,off,part);
  k_scan2<<<1,64,0,stream>>>(part,off,49);
  k_scan3<<<(NN+255)/256,256,0,stream>>>(part,off,cur);
  k_scatter<<<EE/256,256,0,stream>>>(srcp,dstp,eattr,cur,ssrc,sea);
  k_prepw<<<(4*96*8+64+255)/256,256,0,stream>>>(conv_w,att_src,att_dst,lin_edge,att_edge,Watt,Mm);

  k_mlp1<<<(NN+255)/256,256,0,stream>>>(x,in_w1,in_b1,hproj);
  k_gemm96<<<(NN+63)/64,256,0,stream>>>(hproj,96,in_w2,in_b2,h,96);

  for(int l=0;l<4;l++){
    k_gemm96<<<(NN+63)/64,256,0,stream>>>(h,96,conv_w+(size_t)l*96*96,nullptr,hproj,NPROJ);
    k_att8<<<(NN+255)/256,256,0,stream>>>(h,Watt+(size_t)l*96*8,hproj);
    k_agg<<<(NN+3)/4,256,0,stream>>>(hproj,h,off,ssrc,sea,Mm+l*16,
                                     conv_bias+l*96,nsc+l*96,nbi+l*96);
  }

  k_hd1<<<(3*NZ*96+255)/256,256,0,stream>>>(h,zone,
    (const float*)d_in[16],(const float*)d_in[17],
    (const float*)d_in[22],(const float*)d_in[23],
    (const float*)d_in[28],(const float*)d_in[29], t1b);
  k_hd2<<<(3*NZ*48+255)/256,256,0,stream>>>(t1b,
    (const float*)d_in[18],(const float*)d_in[19],
    (const float*)d_in[24],(const float*)d_in[25],
    (const float*)d_in[30],(const float*)d_in[31], t2b);
  k_hd3<<<(NZ*4+255)/256,256,0,stream>>>(t2b,
    (const float*)d_in[20],(const float*)d_in[21],
    (const float*)d_in[26],(const float*)d_in[27],
    (const float*)d_in[32],(const float*)d_in[33], out);
}

// Round 4
// 654.068 us; speedup vs baseline: 1.6704x; 1.0638x over previous
//
#include <hip/hip_runtime.h>

#define NN 50000
#define EE 800000
#define HIDD 96
#define NPROJ 104
#define NZ 384   // BATCH*NUM_ZONES

__device__ __forceinline__ float warp_max64(float v){
  #pragma unroll
  for(int m=1;m<64;m<<=1) v=fmaxf(v,__shfl_xor(v,m));
  return v;
}
__device__ __forceinline__ float warp_sum64(float v){
  #pragma unroll
  for(int m=1;m<64;m<<=1) v+=__shfl_xor(v,m);
  return v;
}

// ---------- CSR build ----------
__global__ void k_deg(const int* __restrict__ dst, int* __restrict__ deg){
  int e=blockIdx.x*blockDim.x+threadIdx.x;
  if(e>=EE) return;
  atomicAdd(&deg[dst[e]],1);
}

__global__ void k_scan1(const int* __restrict__ deg, int* __restrict__ off, int* __restrict__ part){
  __shared__ int sd[256];
  int t=threadIdx.x, b=blockIdx.x;
  int base=b*1024+t*4;
  int v0=(base+0<NN)?deg[base+0]:0;
  int v1=(base+1<NN)?deg[base+1]:0;
  int v2=(base+2<NN)?deg[base+2]:0;
  int v3=(base+3<NN)?deg[base+3]:0;
  int s=v0+v1+v2+v3;
  sd[t]=s; __syncthreads();
  for(int o=1;o<256;o<<=1){
    int x=(t>=o)?sd[t-o]:0;
    __syncthreads();
    sd[t]+=x;
    __syncthreads();
  }
  int ep=sd[t]-s;
  if(base+0<NN) off[base+0]=ep;
  if(base+1<NN) off[base+1]=ep+v0;
  if(base+2<NN) off[base+2]=ep+v0+v1;
  if(base+3<NN) off[base+3]=ep+v0+v1+v2;
  if(t==255) part[b]=sd[255];
}

__global__ void k_scan2(int* part, int* off, int nb){
  if(threadIdx.x==0&&blockIdx.x==0){
    int run=0;
    for(int i=0;i<nb;i++){ int x=part[i]; part[i]=run; run+=x; }
    off[NN]=run;
  }
}

__global__ void k_scan3(const int* __restrict__ part, int* __restrict__ off, int* __restrict__ cur){
  int i=blockIdx.x*blockDim.x+threadIdx.x;
  if(i<NN){ int v=off[i]+part[i>>10]; off[i]=v; cur[i]=v; }
}

__global__ void k_scatter(const int* __restrict__ src, const int* __restrict__ dst,
                          const float* __restrict__ eattr, int* __restrict__ cur,
                          int* __restrict__ ssrc, float* __restrict__ sea){
  int e=blockIdx.x*blockDim.x+threadIdx.x;
  if(e>=EE) return;
  int d=dst[e];
  int p=atomicAdd(&cur[d],1);
  ssrc[p]=src[e];
  *(float4*)(sea+(size_t)p*4)=*(const float4*)(eattr+(size_t)e*4);
}

// ---------- weight prep ----------
__global__ void k_prepw(const float* __restrict__ conv_w, const float* __restrict__ a_src,
                        const float* __restrict__ a_dst, const float* __restrict__ lin_e,
                        const float* __restrict__ a_e,
                        float* __restrict__ Watt, float* __restrict__ Mm){
  int t=blockIdx.x*blockDim.x+threadIdx.x;
  const int WT=4*96*8;
  if(t<WT){
    int l=t/(96*8); int rem=t-l*(96*8); int k=rem>>3; int j=rem&7;
    int hh=j&3;
    const float* W=conv_w+(size_t)l*96*96+(size_t)k*96;
    const float* a=((j>=4)?a_dst:a_src)+l*96+hh*24;
    float v=0.f;
    #pragma unroll
    for(int c=0;c<24;c++) v+=W[hh*24+c]*a[c];
    Watt[t]=v;
  } else if(t<WT+64){
    int q=t-WT; int l=q>>4; int i=(q>>2)&3; int hh=q&3;
    const float* We=lin_e+(size_t)l*4*96+(size_t)i*96;
    const float* a=a_e+l*96+hh*24;
    float v=0.f;
    #pragma unroll
    for(int c=0;c<24;c++) v+=We[hh*24+c]*a[c];
    Mm[q]=v;  // M[l][i][h]
  }
}

// ---------- input MLP layer 1 ----------
__global__ void k_mlp1(const float* __restrict__ x, const float* __restrict__ w,
                       const float* __restrict__ b, float* __restrict__ out){
  int i=blockIdx.x*blockDim.x+threadIdx.x;
  if(i>=NN) return;
  float xv[12];
  #pragma unroll
  for(int k=0;k<12;k++) xv[k]=x[(size_t)i*12+k];
  for(int j=0;j<HIDD;j++){
    float a=b[j];
    #pragma unroll
    for(int k=0;k<12;k++) a+=xv[k]*w[k*HIDD+j];
    out[(size_t)i*HIDD+j]=fmaxf(a,0.f);
  }
}

// ---------- GEMM: C[N][96] = A[N][96] @ W[96][96] (+bias) ----------
__global__ __launch_bounds__(256) void k_gemm96(const float* __restrict__ A, int lda,
                                                const float* __restrict__ W,
                                                const float* __restrict__ bias,
                                                float* __restrict__ C, int ldc){
  __shared__ float As[64][100];
  __shared__ float Ws[96][96];
  int t=threadIdx.x;
  int r0=blockIdx.x*64;
  for(int i=t;i<96*96/4;i+=256) ((float4*)&Ws[0][0])[i]=((const float4*)W)[i];
  for(int i=t;i<64*24;i+=256){
    int rr=i/24, cc=(i-rr*24)*4; int g=r0+rr;
    float4 v = (g<NN)? *(const float4*)(A+(size_t)g*lda+cc) : float4{0.f,0.f,0.f,0.f};
    *(float4*)&As[rr][cc]=v;
  }
  __syncthreads();
  int cg=t&15, rg=t>>4;
  int c0=cg*6, r=rg*4;
  float acc[4][6];
  #pragma unroll
  for(int i=0;i<4;i++)
    #pragma unroll
    for(int j=0;j<6;j++) acc[i][j]=0.f;
  for(int k4=0;k4<96;k4+=4){
    float4 a0=*(float4*)&As[r  ][k4];
    float4 a1=*(float4*)&As[r+1][k4];
    float4 a2=*(float4*)&As[r+2][k4];
    float4 a3=*(float4*)&As[r+3][k4];
    #pragma unroll
    for(int kk=0;kk<4;kk++){
      float2 w01=*(float2*)&Ws[k4+kk][c0];
      float2 w23=*(float2*)&Ws[k4+kk][c0+2];
      float2 w45=*(float2*)&Ws[k4+kk][c0+4];
      float wv[6]={w01.x,w01.y,w23.x,w23.y,w45.x,w45.y};
      float av0=((float*)&a0)[kk],av1=((float*)&a1)[kk],av2=((float*)&a2)[kk],av3=((float*)&a3)[kk];
      #pragma unroll
      for(int j=0;j<6;j++){
        acc[0][j]+=av0*wv[j];
        acc[1][j]+=av1*wv[j];
        acc[2][j]+=av2*wv[j];
        acc[3][j]+=av3*wv[j];
      }
    }
  }
  #pragma unroll
  for(int i=0;i<4;i++){
    int g=r0+r+i;
    if(g<NN){
      #pragma unroll
      for(int j=0;j<6;j++) C[(size_t)g*ldc+c0+j]=acc[i][j]+(bias?bias[c0+j]:0.f);
    }
  }
}

// ---------- attention logit columns ----------
__global__ __launch_bounds__(256) void k_att8(const float* __restrict__ h, const float* __restrict__ W8,
                                              float* __restrict__ hproj){
  __shared__ float ws[96*8];
  int t=threadIdx.x;
  for(int i=t;i<768;i+=256) ws[i]=W8[i];
  __syncthreads();
  int n=blockIdx.x*256+t;
  if(n>=NN) return;
  float acc[8];
  #pragma unroll
  for(int j=0;j<8;j++) acc[j]=0.f;
  for(int k4=0;k4<24;k4++){
    float4 v=*(const float4*)(h+(size_t)n*96+k4*4);
    #pragma unroll
    for(int kk=0;kk<4;kk++){
      float a=((float*)&v)[kk];
      #pragma unroll
      for(int j=0;j<8;j++) acc[j]+=a*ws[(k4*4+kk)*8+j];
    }
  }
  #pragma unroll
  for(int j=0;j<8;j++) hproj[(size_t)n*NPROJ+96+j]=acc[j];
}

// ---------- fused GAT agg + self-loop + bias + ELU + residual + LN ----------
// wave per node. alpha phase: 64-wide over edges. gather phase: 4x16-lane
// subgroups, lane sl owns dims 6sl..6sl+5 (head hL=sl>>2), e/rowoff via LDS
// broadcast reads. Partial acc merged via shfl_xor(16/32).
__global__ __launch_bounds__(256) void k_agg(const float* __restrict__ hproj, float* __restrict__ h,
    const int* __restrict__ off, const int* __restrict__ ssrc, const float* __restrict__ sea,
    const float* __restrict__ Mm,
    const float* __restrict__ bias, const float* __restrict__ nsc, const float* __restrict__ nbi){
  __shared__ float earr[4][256];
  __shared__ int   sarr[4][64];
  int wid=threadIdx.x>>6, lane=threadIdx.x&63;
  int sub=lane>>4, sl=lane&15;
  int n=blockIdx.x*4+wid;
  if(n>=NN) return;
  float M[16];
  #pragma unroll
  for(int i=0;i<16;i++) M[i]=Mm[i];
  const float4 ad=*(const float4*)(hproj+(size_t)n*NPROJ+100);
  int b0=off[n]; int deg=off[n+1]-b0;
  float invdeg=1.f/(float)(deg>0?deg:1);
  float m0=-INFINITY,m1=-INFINITY,m2=-INFINITY,m3=-INFINITY;
  float d0=0.f,d1=0.f,d2=0.f,d3=0.f;
  float acc[6]={0.f,0.f,0.f,0.f,0.f,0.f};
  float sx=0.f,sy=0.f,sz=0.f,sw=0.f;
  int hL=sl>>2;
  const char* hpb=(const char*)hproj;

  for(int cs=0;cs<deg;cs+=64){
    int idx=cs+lane;
    bool valid=idx<deg;
    float a0=-INFINITY,a1=-INFINITY,a2=-INFINITY,a3=-INFINITY;
    int rowoff=n*(NPROJ*4);
    if(valid){
      int ei=b0+idx;
      rowoff=ssrc[ei]*(NPROJ*4);
      float4 ea=*(const float4*)(sea+(size_t)ei*4);
      sx+=ea.x; sy+=ea.y; sz+=ea.z; sw+=ea.w;
      const float4 as=*(const float4*)(hpb+(size_t)(unsigned)rowoff+96*4);
      a0=as.x+ad.x+ea.x*M[0]+ea.y*M[4]+ea.z*M[8] +ea.w*M[12];
      a1=as.y+ad.y+ea.x*M[1]+ea.y*M[5]+ea.z*M[9] +ea.w*M[13];
      a2=as.z+ad.z+ea.x*M[2]+ea.y*M[6]+ea.z*M[10]+ea.w*M[14];
      a3=as.w+ad.w+ea.x*M[3]+ea.y*M[7]+ea.z*M[11]+ea.w*M[15];
      a0=a0>0.f?a0:0.2f*a0; a1=a1>0.f?a1:0.2f*a1;
      a2=a2>0.f?a2:0.2f*a2; a3=a3>0.f?a3:0.2f*a3;
    }
    float c0=warp_max64(a0),c1=warp_max64(a1),c2=warp_max64(a2),c3=warp_max64(a3);
    float nm0=fmaxf(m0,c0),nm1=fmaxf(m1,c1),nm2=fmaxf(m2,c2),nm3=fmaxf(m3,c3);
    float s0=expf(m0-nm0),s1=expf(m1-nm1),s2=expf(m2-nm2),s3=expf(m3-nm3);
    d0*=s0; d1*=s1; d2*=s2; d3*=s3;
    float scL=(hL==0)?s0:((hL==1)?s1:((hL==2)?s2:s3));
    #pragma unroll
    for(int c=0;c<6;c++) acc[c]*=scL;
    m0=nm0;m1=nm1;m2=nm2;m3=nm3;
    float e0=valid?expf(a0-nm0):0.f;
    float e1=valid?expf(a1-nm1):0.f;
    float e2=valid?expf(a2-nm2):0.f;
    float e3=valid?expf(a3-nm3):0.f;
    d0+=warp_sum64(e0); d1+=warp_sum64(e1); d2+=warp_sum64(e2); d3+=warp_sum64(e3);
    *(float4*)&earr[wid][lane*4]=float4{e0,e1,e2,e3};
    sarr[wid][lane]=rowoff;
    int nc=deg-cs; if(nc>64) nc=64;
    for(int jj=0;jj<nc;jj+=4){
      int j=jj+sub;
      if(j<nc){
        int ro=sarr[wid][j];
        float ev=earr[wid][(j<<2)+hL];
        const char* rp=hpb+(size_t)(unsigned)ro+(size_t)sl*24;
        float2 h01=*(const float2*)(rp);
        float2 h23=*(const float2*)(rp+8);
        float2 h45=*(const float2*)(rp+16);
        acc[0]+=ev*h01.x; acc[1]+=ev*h01.y;
        acc[2]+=ev*h23.x; acc[3]+=ev*h23.y;
        acc[4]+=ev*h45.x; acc[5]+=ev*h45.y;
      }
    }
  }
  // merge subgroup partial accumulators (all lanes end with the full sum)
  #pragma unroll
  for(int c=0;c<6;c++){
    acc[c]+=__shfl_xor(acc[c],16);
    acc[c]+=__shfl_xor(acc[c],32);
  }
  // edge-attr means for self-loop
  sx=warp_sum64(sx); sy=warp_sum64(sy); sz=warp_sum64(sz); sw=warp_sum64(sw);
  float lx=sx*invdeg, ly=sy*invdeg, lz=sz*invdeg, lw=sw*invdeg;
  const float4 aself=*(const float4*)(hproj+(size_t)n*NPROJ+96);
  float b0a=aself.x+ad.x+lx*M[0]+ly*M[4]+lz*M[8] +lw*M[12];
  float b1a=aself.y+ad.y+lx*M[1]+ly*M[5]+lz*M[9] +lw*M[13];
  float b2a=aself.z+ad.z+lx*M[2]+ly*M[6]+lz*M[10]+lw*M[14];
  float b3a=aself.w+ad.w+lx*M[3]+ly*M[7]+lz*M[11]+lw*M[15];
  b0a=b0a>0.f?b0a:0.2f*b0a; b1a=b1a>0.f?b1a:0.2f*b1a;
  b2a=b2a>0.f?b2a:0.2f*b2a; b3a=b3a>0.f?b3a:0.2f*b3a;
  float nm0=fmaxf(m0,b0a),nm1=fmaxf(m1,b1a),nm2=fmaxf(m2,b2a),nm3=fmaxf(m3,b3a);
  float s0=expf(m0-nm0),s1=expf(m1-nm1),s2=expf(m2-nm2),s3=expf(m3-nm3);
  float e0=expf(b0a-nm0),e1=expf(b1a-nm1),e2=expf(b2a-nm2),e3=expf(b3a-nm3);
  d0=d0*s0+e0; d1=d1*s1+e1; d2=d2*s2+e2; d3=d3*s3+e3;
  float scL=(hL==0)?s0:((hL==1)?s1:((hL==2)?s2:s3));
  float eL =(hL==0)?e0:((hL==1)?e1:((hL==2)?e2:e3));
  const float* selfrow=hproj+(size_t)n*NPROJ+(size_t)sl*6;
  float2 q01=*(const float2*)(selfrow);
  float2 q23=*(const float2*)(selfrow+2);
  float2 q45=*(const float2*)(selfrow+4);
  acc[0]=acc[0]*scL+eL*q01.x; acc[1]=acc[1]*scL+eL*q01.y;
  acc[2]=acc[2]*scL+eL*q23.x; acc[3]=acc[3]*scL+eL*q23.y;
  acc[4]=acc[4]*scL+eL*q45.x; acc[5]=acc[5]*scL+eL*q45.y;
  // epilogue: /den + bias -> ELU -> +residual -> LayerNorm
  float dL=(hL==0)?d0:((hL==1)?d1:((hL==2)?d2:d3));
  float rinv=1.f/(dL+1e-16f);
  const float* hrow=h+(size_t)n*HIDD+(size_t)sl*6;
  float2 r01=*(const float2*)(hrow);
  float2 r23=*(const float2*)(hrow+2);
  float2 r45=*(const float2*)(hrow+4);
  const float* bp=bias+sl*6;
  float t[6];
  float rr[6]={r01.x,r01.y,r23.x,r23.y,r45.x,r45.y};
  #pragma unroll
  for(int c=0;c<6;c++){
    float v=acc[c]*rinv+bp[c];
    v=v>0.f?v:expm1f(v);
    t[c]=v+rr[c];
  }
  float s1l=t[0]+t[1]+t[2]+t[3]+t[4]+t[5];
  float s2l=t[0]*t[0]+t[1]*t[1]+t[2]*t[2]+t[3]*t[3]+t[4]*t[4]+t[5]*t[5];
  #pragma unroll
  for(int m=1;m<16;m<<=1){ s1l+=__shfl_xor(s1l,m); s2l+=__shfl_xor(s2l,m); }
  float mean=s1l*(1.f/96.f);
  float var=s2l*(1.f/96.f)-mean*mean;
  float rs=rsqrtf(var+1e-5f);
  if(sub==0){
    float* op=h+(size_t)n*HIDD+(size_t)sl*6;
    const float* sc=nsc+sl*6;
    const float* bi=nbi+sl*6;
    float o[6];
    #pragma unroll
    for(int c=0;c<6;c++) o[c]=(t[c]-mean)*rs*sc[c]+bi[c];
    *(float2*)(op)  =float2{o[0],o[1]};
    *(float2*)(op+2)=float2{o[2],o[3]};
    *(float2*)(op+4)=float2{o[4],o[5]};
  }
}

// ---------- prediction heads ----------
__global__ __launch_bounds__(256) void k_hd1(const float* __restrict__ h, const int* __restrict__ zone,
    const float* __restrict__ cw1,const float* __restrict__ cb1,
    const float* __restrict__ dw1,const float* __restrict__ db1,
    const float* __restrict__ jw1,const float* __restrict__ jb1,
    float* __restrict__ t1){
  int idx=blockIdx.x*256+threadIdx.x;
  if(idx>=3*NZ*96) return;
  int hd=idx/(NZ*96); int rem=idx-hd*(NZ*96); int row=rem/96; int j=rem-row*96;
  const float* w1=(hd==0)?cw1:((hd==1)?dw1:jw1);
  const float* b1=(hd==0)?cb1:((hd==1)?db1:jb1);
  int n=zone[row];
  const float* hr=h+(size_t)n*96;
  float acc=b1[j];
  #pragma unroll
  for(int k4=0;k4<24;k4++){
    float4 hv=*(const float4*)(hr+k4*4);
    acc+=hv.x*w1[(k4*4+0)*96+j];
    acc+=hv.y*w1[(k4*4+1)*96+j];
    acc+=hv.z*w1[(k4*4+2)*96+j];
    acc+=hv.w*w1[(k4*4+3)*96+j];
  }
  t1[idx]=fmaxf(acc,0.f);
}

__global__ __launch_bounds__(256) void k_hd2(const float* __restrict__ t1,
    const float* __restrict__ cw2,const float* __restrict__ cb2,
    const float* __restrict__ dw2,const float* __restrict__ db2,
    const float* __restrict__ jw2,const float* __restrict__ jb2,
    float* __restrict__ t2){
  int idx=blockIdx.x*256+threadIdx.x;
  if(idx>=3*NZ*48) return;
  int hd=idx/(NZ*48); int rem=idx-hd*(NZ*48); int row=rem/48; int c=rem-row*48;
  const float* w2=(hd==0)?cw2:((hd==1)?dw2:jw2);
  const float* b2=(hd==0)?cb2:((hd==1)?db2:jb2);
  const float* t1r=t1+(size_t)hd*NZ*96+(size_t)row*96;
  float acc=b2[c];
  #pragma unroll
  for(int k4=0;k4<24;k4++){
    float4 tv=*(const float4*)(t1r+k4*4);
    acc+=tv.x*w2[(k4*4+0)*48+c];
    acc+=tv.y*w2[(k4*4+1)*48+c];
    acc+=tv.z*w2[(k4*4+2)*48+c];
    acc+=tv.w*w2[(k4*4+3)*48+c];
  }
  t2[idx]=fmaxf(acc,0.f);
}

__global__ __launch_bounds__(256) void k_hd3(const float* __restrict__ t2,
    const float* __restrict__ cw3,const float* __restrict__ cb3,
    const float* __restrict__ dw3,const float* __restrict__ db3,
    const float* __restrict__ jw3,const float* __restrict__ jb3,
    float* __restrict__ out){
  int idx=blockIdx.x*256+threadIdx.x;
  if(idx>=NZ*4) return;
  int row=idx>>2, o=idx&3;
  int hd=(o<2)?0:((o==2)?1:2);
  int c=(o<2)?o:0;
  int osz=(hd==0)?2:1;
  const float* w3=(hd==0)?cw3:((hd==1)?dw3:jw3);
  const float* b3=(hd==0)?cb3:((hd==1)?db3:jb3);
  const float* t2r=t2+(size_t)hd*NZ*48+(size_t)row*48;
  float acc=b3[c];
  #pragma unroll
  for(int k=0;k<48;k++) acc+=t2r[k]*w3[k*osz+c];
  out[idx]=acc;
}

extern "C" void kernel_launch(void* const* d_in, const int* in_sizes, int n_in,
                              void* d_out, int out_size, void* d_ws, size_t ws_size,
                              hipStream_t stream){
  const float* x       =(const float*)d_in[0];
  const int*   eidx    =(const int*)  d_in[1];
  const float* eattr   =(const float*)d_in[2];
  const int*   zone    =(const int*)  d_in[3];
  const float* in_w1   =(const float*)d_in[4];
  const float* in_b1   =(const float*)d_in[5];
  const float* in_w2   =(const float*)d_in[6];
  const float* in_b2   =(const float*)d_in[7];
  const float* conv_w  =(const float*)d_in[8];
  const float* att_src =(const float*)d_in[9];
  const float* att_dst =(const float*)d_in[10];
  const float* lin_edge=(const float*)d_in[11];
  const float* att_edge=(const float*)d_in[12];
  const float* conv_bias=(const float*)d_in[13];
  const float* nsc     =(const float*)d_in[14];
  const float* nbi     =(const float*)d_in[15];
  float* out=(float*)d_out;

  char* p=(char*)d_ws;
  auto carve=[&](size_t bytes)->char*{ char* r=p; p+=(bytes+255)&~(size_t)255; return r; };
  float* h    =(float*)carve((size_t)NN*96*4);
  float* hproj=(float*)carve((size_t)NN*104*4);
  int*   ssrc =(int*)  carve((size_t)EE*4);
  float* sea  =(float*)carve((size_t)EE*16);
  int*   deg  =(int*)  carve((size_t)NN*4);
  int*   off  =(int*)  carve((size_t)(NN+1)*4);
  int*   cur  =(int*)  carve((size_t)NN*4);
  float* Watt =(float*)carve((size_t)4*96*8*4);
  float* Mm   =(float*)carve(64*4);
  int*   part =(int*)  carve(64*4);
  float* t1b  =(float*)carve((size_t)3*NZ*96*4);
  float* t2b  =(float*)carve((size_t)3*NZ*48*4);

  const int* srcp=eidx;
  const int* dstp=eidx+EE;

  hipMemsetAsync(deg,0,(size_t)NN*4,stream);
  k_deg<<<EE/256,256,0,stream>>>(dstp,deg);
  k_scan1<<<49,256,0,stream>>>(deg,off,part);
  k_scan2<<<1,64,0,stream>>>(part,off,49);
  k_scan3<<<(NN+255)/256,256,0,stream>>>(part,off,cur);
  k_scatter<<<EE/256,256,0,stream>>>(srcp,dstp,eattr,cur,ssrc,sea);
  k_prepw<<<(4*96*8+64+255)/256,256,0,stream>>>(conv_w,att_src,att_dst,lin_edge,att_edge,Watt,Mm);

  k_mlp1<<<(NN+255)/256,256,0,stream>>>(x,in_w1,in_b1,hproj);
  k_gemm96<<<(NN+63)/64,256,0,stream>>>(hproj,96,in_w2,in_b2,h,96);

  for(int l=0;l<4;l++){
    k_gemm96<<<(NN+63)/64,256,0,stream>>>(h,96,conv_w+(size_t)l*96*96,nullptr,hproj,NPROJ);
    k_att8<<<(NN+255)/256,256,0,stream>>>(h,Watt+(size_t)l*96*8,hproj);
    k_agg<<<(NN+3)/4,256,0,stream>>>(hproj,h,off,ssrc,sea,Mm+l*16,
                                     conv_bias+l*96,nsc+l*96,nbi+l*96);
  }

  k_hd1<<<(3*NZ*96+255)/256,256,0,stream>>>(h,zone,
    (const float*)d_in[16],(const float*)d_in[17],
    (const float*)d_in[22],(const float*)d_in[23],
    (const float*)d_in[28],(const float*)d_in[29], t1b);
  k_hd2<<<(3*NZ*48+255)/256,256,0,stream>>>(t1b,
    (const float*)d_in[18],(const float*)d_in[19],
    (const float*)d_in[24],(const float*)d_in[25],
    (const float*)d_in[30],(const float*)d_in[31], t2b);
  k_hd3<<<(NZ*4+255)/256,256,0,stream>>>(t2b,
    (const float*)d_in[20],(const float*)d_in[21],
    (const float*)d_in[26],(const float*)d_in[27],
    (const float*)d_in[32],(const float*)d_in[33], out);
}

// Round 5
// 454.003 us; speedup vs baseline: 2.4065x; 1.4407x over previous
//
#include <hip/hip_runtime.h>
#include <hip/hip_fp16.h>

#define NN 50000
#define EE 800000
#define HIDD 96
#define NZ 384   // BATCH*NUM_ZONES

// ---------- CSR build ----------
__global__ void k_deg(const int* __restrict__ dst, int* __restrict__ deg){
  int e=blockIdx.x*blockDim.x+threadIdx.x;
  if(e>=EE) return;
  atomicAdd(&deg[dst[e]],1);
}

__global__ void k_scan1(const int* __restrict__ deg, int* __restrict__ off, int* __restrict__ part){
  __shared__ int sd[256];
  int t=threadIdx.x, b=blockIdx.x;
  int base=b*1024+t*4;
  int v0=(base+0<NN)?deg[base+0]:0;
  int v1=(base+1<NN)?deg[base+1]:0;
  int v2=(base+2<NN)?deg[base+2]:0;
  int v3=(base+3<NN)?deg[base+3]:0;
  int s=v0+v1+v2+v3;
  sd[t]=s; __syncthreads();
  for(int o=1;o<256;o<<=1){
    int x=(t>=o)?sd[t-o]:0;
    __syncthreads();
    sd[t]+=x;
    __syncthreads();
  }
  int ep=sd[t]-s;
  if(base+0<NN) off[base+0]=ep;
  if(base+1<NN) off[base+1]=ep+v0;
  if(base+2<NN) off[base+2]=ep+v0+v1;
  if(base+3<NN) off[base+3]=ep+v0+v1+v2;
  if(t==255) part[b]=sd[255];
}

__global__ void k_scan2(int* part, int* off, int nb){
  if(threadIdx.x==0&&blockIdx.x==0){
    int run=0;
    for(int i=0;i<nb;i++){ int x=part[i]; part[i]=run; run+=x; }
    off[NN]=run;
  }
}

__global__ void k_scan3(const int* __restrict__ part, int* __restrict__ off, int* __restrict__ cur){
  int i=blockIdx.x*blockDim.x+threadIdx.x;
  if(i<NN){ int v=off[i]+part[i>>10]; off[i]=v; cur[i]=v; }
}

__global__ void k_scatter(const int* __restrict__ src, const int* __restrict__ dst,
                          const float* __restrict__ eattr, int* __restrict__ cur,
                          int* __restrict__ ssrc, float* __restrict__ sea){
  int e=blockIdx.x*blockDim.x+threadIdx.x;
  if(e>=EE) return;
  int d=dst[e];
  int p=atomicAdd(&cur[d],1);
  ssrc[p]=src[e];
  *(float4*)(sea+(size_t)p*4)=*(const float4*)(eattr+(size_t)e*4);
}

// ---------- weight prep ----------
__global__ void k_prepw(const float* __restrict__ conv_w, const float* __restrict__ a_src,
                        const float* __restrict__ a_dst, const float* __restrict__ lin_e,
                        const float* __restrict__ a_e,
                        float* __restrict__ Watt, float* __restrict__ Mm){
  int t=blockIdx.x*blockDim.x+threadIdx.x;
  const int WT=4*96*8;
  if(t<WT){
    int l=t/(96*8); int rem=t-l*(96*8); int k=rem>>3; int j=rem&7;
    int hh=j&3;
    const float* W=conv_w+(size_t)l*96*96+(size_t)k*96;
    const float* a=((j>=4)?a_dst:a_src)+l*96+hh*24;
    float v=0.f;
    #pragma unroll
    for(int c=0;c<24;c++) v+=W[hh*24+c]*a[c];
    Watt[t]=v;
  } else if(t<WT+64){
    int q=t-WT; int l=q>>4; int i=(q>>2)&3; int hh=q&3;
    const float* We=lin_e+(size_t)l*4*96+(size_t)i*96;
    const float* a=a_e+l*96+hh*24;
    float v=0.f;
    #pragma unroll
    for(int c=0;c<24;c++) v+=We[hh*24+c]*a[c];
    Mm[q]=v;  // M[l][i][h]
  }
}

// ---------- input MLP layer 1 ----------
__global__ void k_mlp1(const float* __restrict__ x, const float* __restrict__ w,
                       const float* __restrict__ b, float* __restrict__ out){
  int i=blockIdx.x*blockDim.x+threadIdx.x;
  if(i>=NN) return;
  float xv[12];
  #pragma unroll
  for(int k=0;k<12;k++) xv[k]=x[(size_t)i*12+k];
  for(int j=0;j<HIDD;j++){
    float a=b[j];
    #pragma unroll
    for(int k=0;k<12;k++) a+=xv[k]*w[k*HIDD+j];
    out[(size_t)i*HIDD+j]=fmaxf(a,0.f);
  }
}

// ---------- GEMM: C[N][96] = A[N][96] @ W[96][96] (+bias), fp32 or fp16 out ----------
template<bool H16>
__global__ __launch_bounds__(256) void k_gemm96(const float* __restrict__ A, int lda,
                                                const float* __restrict__ W,
                                                const float* __restrict__ bias,
                                                void* __restrict__ Cv, int ldc){
  __shared__ float As[64][100];
  __shared__ float Ws[96][96];
  int t=threadIdx.x;
  int r0=blockIdx.x*64;
  for(int i=t;i<96*96/4;i+=256) ((float4*)&Ws[0][0])[i]=((const float4*)W)[i];
  for(int i=t;i<64*24;i+=256){
    int rr=i/24, cc=(i-rr*24)*4; int g=r0+rr;
    float4 v = (g<NN)? *(const float4*)(A+(size_t)g*lda+cc) : float4{0.f,0.f,0.f,0.f};
    *(float4*)&As[rr][cc]=v;
  }
  __syncthreads();
  int cg=t&15, rg=t>>4;
  int c0=cg*6, r=rg*4;
  float acc[4][6];
  #pragma unroll
  for(int i=0;i<4;i++)
    #pragma unroll
    for(int j=0;j<6;j++) acc[i][j]=0.f;
  for(int k4=0;k4<96;k4+=4){
    float4 a0=*(float4*)&As[r  ][k4];
    float4 a1=*(float4*)&As[r+1][k4];
    float4 a2=*(float4*)&As[r+2][k4];
    float4 a3=*(float4*)&As[r+3][k4];
    #pragma unroll
    for(int kk=0;kk<4;kk++){
      float2 w01=*(float2*)&Ws[k4+kk][c0];
      float2 w23=*(float2*)&Ws[k4+kk][c0+2];
      float2 w45=*(float2*)&Ws[k4+kk][c0+4];
      float wv[6]={w01.x,w01.y,w23.x,w23.y,w45.x,w45.y};
      float av0=((float*)&a0)[kk],av1=((float*)&a1)[kk],av2=((float*)&a2)[kk],av3=((float*)&a3)[kk];
      #pragma unroll
      for(int j=0;j<6;j++){
        acc[0][j]+=av0*wv[j];
        acc[1][j]+=av1*wv[j];
        acc[2][j]+=av2*wv[j];
        acc[3][j]+=av3*wv[j];
      }
    }
  }
  #pragma unroll
  for(int i=0;i<4;i++){
    int g=r0+r+i;
    if(g<NN){
      if(H16){
        __half* C=(__half*)Cv;
        #pragma unroll
        for(int jp=0;jp<3;jp++){
          __half2 pk=__floats2half2_rn(acc[i][2*jp],acc[i][2*jp+1]);
          *(__half2*)(C+(size_t)g*ldc+c0+2*jp)=pk;
        }
      }else{
        float* C=(float*)Cv;
        #pragma unroll
        for(int j=0;j<6;j++) C[(size_t)g*ldc+c0+j]=acc[i][j]+(bias?bias[c0+j]:0.f);
      }
    }
  }
}

// ---------- attention logit columns: att[n][0..8) = h[n][:] @ W8[96][8] ----------
__global__ __launch_bounds__(256) void k_att8(const float* __restrict__ h, const float* __restrict__ W8,
                                              float* __restrict__ att){
  __shared__ float ws[96*8];
  int t=threadIdx.x;
  for(int i=t;i<768;i+=256) ws[i]=W8[i];
  __syncthreads();
  int n=blockIdx.x*256+t;
  if(n>=NN) return;
  float acc[8];
  #pragma unroll
  for(int j=0;j<8;j++) acc[j]=0.f;
  for(int k4=0;k4<24;k4++){
    float4 v=*(const float4*)(h+(size_t)n*96+k4*4);
    #pragma unroll
    for(int kk=0;kk<4;kk++){
      float a=((float*)&v)[kk];
      #pragma unroll
      for(int j=0;j<8;j++) acc[j]+=a*ws[(k4*4+kk)*8+j];
    }
  }
  #pragma unroll
  for(int j=0;j<8;j++) att[(size_t)n*8+j]=acc[j];
}

// ---------- fused GAT agg (no-max softmax) + self-loop + bias + ELU + residual + LN ----------
// 16-lane subgroup per node; block = 256 threads = 16 nodes.
// lane sl owns dims 6sl..6sl+5 (head hL=sl>>2). hp16 = fp16 [NN][96] rows (192B).
__global__ __launch_bounds__(256) void k_agg(const __half* __restrict__ hp16,
    const float* __restrict__ att, float* __restrict__ h,
    const int* __restrict__ off, const int* __restrict__ ssrc, const float* __restrict__ sea,
    const float* __restrict__ Mm, const float* __restrict__ bias,
    const float* __restrict__ nsc, const float* __restrict__ nbi){
  __shared__ float w4[16][17][4];
  __shared__ int   roA[16][17];
  int tid=threadIdx.x;
  int sg=tid>>4, sl=tid&15;
  int n=blockIdx.x*16+sg;
  if(n>=NN) return;
  float M[16];
  #pragma unroll
  for(int i=0;i<16;i++) M[i]=Mm[i];
  const float4 ad=*(const float4*)(att+(size_t)n*8+4);
  int b0=off[n], deg=off[n+1]-b0;
  float invdeg=1.f/(float)(deg>0?deg:1);
  int hL=sl>>2;
  int sloff=sl*12;
  float ds0=0.f,ds1=0.f,ds2=0.f,ds3=0.f;
  float sx=0.f,sy=0.f,sz=0.f,sw=0.f;
  float acc[6]={0.f,0.f,0.f,0.f,0.f,0.f};
  const char* hb=(const char*)hp16;

  for(int cs=0;cs<deg;cs+=16){
    int idx=cs+sl;
    bool valid=idx<deg;
    float w0=0.f,w1=0.f,w2=0.f,w3=0.f; int ro=0;
    if(valid){
      int ei=b0+idx;
      int s=ssrc[ei];
      ro=s*192;
      float4 ea=*(const float4*)(sea+(size_t)ei*4);
      sx+=ea.x; sy+=ea.y; sz+=ea.z; sw+=ea.w;
      const float4 as=*(const float4*)(att+(size_t)s*8);
      float a0=as.x+ad.x+ea.x*M[0]+ea.y*M[4]+ea.z*M[8] +ea.w*M[12];
      float a1=as.y+ad.y+ea.x*M[1]+ea.y*M[5]+ea.z*M[9] +ea.w*M[13];
      float a2=as.z+ad.z+ea.x*M[2]+ea.y*M[6]+ea.z*M[10]+ea.w*M[14];
      float a3=as.w+ad.w+ea.x*M[3]+ea.y*M[7]+ea.z*M[11]+ea.w*M[15];
      a0=a0>0.f?a0:0.2f*a0; a1=a1>0.f?a1:0.2f*a1;
      a2=a2>0.f?a2:0.2f*a2; a3=a3>0.f?a3:0.2f*a3;
      w0=__expf(a0); w1=__expf(a1); w2=__expf(a2); w3=__expf(a3);
      ds0+=w0; ds1+=w1; ds2+=w2; ds3+=w3;
    }
    *(float4*)&w4[sg][sl][0]=float4{w0,w1,w2,w3};
    roA[sg][sl]=ro;
    int nc=deg-cs; if(nc>16) nc=16;
    for(int j=0;j<nc;j++){
      float ev=w4[sg][j][hL];
      const char* rp=hb+(size_t)(unsigned)roA[sg][j]+sloff;
      uint3 u=*(const uint3*)rp;
      __half2 q0=*(__half2*)&u.x, q1=*(__half2*)&u.y, q2=*(__half2*)&u.z;
      float2 f0=__half22float2(q0), f1=__half22float2(q1), f2=__half22float2(q2);
      acc[0]+=ev*f0.x; acc[1]+=ev*f0.y;
      acc[2]+=ev*f1.x; acc[3]+=ev*f1.y;
      acc[4]+=ev*f2.x; acc[5]+=ev*f2.y;
    }
  }
  // 16-lane reductions (denominators + edge-attr sums)
  #pragma unroll
  for(int m=1;m<16;m<<=1){
    ds0+=__shfl_xor(ds0,m); ds1+=__shfl_xor(ds1,m);
    ds2+=__shfl_xor(ds2,m); ds3+=__shfl_xor(ds3,m);
    sx +=__shfl_xor(sx ,m); sy +=__shfl_xor(sy ,m);
    sz +=__shfl_xor(sz ,m); sw +=__shfl_xor(sw ,m);
  }
  // self-loop with mean edge-attr
  float lx=sx*invdeg, ly=sy*invdeg, lz=sz*invdeg, lw=sw*invdeg;
  const float4 aself=*(const float4*)(att+(size_t)n*8);
  float b0a=aself.x+ad.x+lx*M[0]+ly*M[4]+lz*M[8] +lw*M[12];
  float b1a=aself.y+ad.y+lx*M[1]+ly*M[5]+lz*M[9] +lw*M[13];
  float b2a=aself.z+ad.z+lx*M[2]+ly*M[6]+lz*M[10]+lw*M[14];
  float b3a=aself.w+ad.w+lx*M[3]+ly*M[7]+lz*M[11]+lw*M[15];
  b0a=b0a>0.f?b0a:0.2f*b0a; b1a=b1a>0.f?b1a:0.2f*b1a;
  b2a=b2a>0.f?b2a:0.2f*b2a; b3a=b3a>0.f?b3a:0.2f*b3a;
  float e0=__expf(b0a),e1=__expf(b1a),e2=__expf(b2a),e3=__expf(b3a);
  ds0+=e0; ds1+=e1; ds2+=e2; ds3+=e3;
  float eL=(hL==0)?e0:((hL==1)?e1:((hL==2)?e2:e3));
  {
    const char* rp=hb+(size_t)n*192+sloff;
    uint3 u=*(const uint3*)rp;
    __half2 q0=*(__half2*)&u.x, q1=*(__half2*)&u.y, q2=*(__half2*)&u.z;
    float2 f0=__half22float2(q0), f1=__half22float2(q1), f2=__half22float2(q2);
    acc[0]+=eL*f0.x; acc[1]+=eL*f0.y;
    acc[2]+=eL*f1.x; acc[3]+=eL*f1.y;
    acc[4]+=eL*f2.x; acc[5]+=eL*f2.y;
  }
  // epilogue: /den + bias -> ELU -> +residual -> LayerNorm (16-lane)
  float dL=(hL==0)?ds0:((hL==1)?ds1:((hL==2)?ds2:ds3));
  float rinv=1.f/(dL+1e-16f);
  const float* hrow=h+(size_t)n*HIDD+(size_t)sl*6;
  float2 r01=*(const float2*)(hrow);
  float2 r23=*(const float2*)(hrow+2);
  float2 r45=*(const float2*)(hrow+4);
  float rr[6]={r01.x,r01.y,r23.x,r23.y,r45.x,r45.y};
  const float* bp=bias+sl*6;
  float t[6];
  #pragma unroll
  for(int c=0;c<6;c++){
    float v=acc[c]*rinv+bp[c];
    v=v>0.f?v:expm1f(v);
    t[c]=v+rr[c];
  }
  float s1l=t[0]+t[1]+t[2]+t[3]+t[4]+t[5];
  float s2l=t[0]*t[0]+t[1]*t[1]+t[2]*t[2]+t[3]*t[3]+t[4]*t[4]+t[5]*t[5];
  #pragma unroll
  for(int m=1;m<16;m<<=1){ s1l+=__shfl_xor(s1l,m); s2l+=__shfl_xor(s2l,m); }
  float mean=s1l*(1.f/96.f);
  float var=s2l*(1.f/96.f)-mean*mean;
  float rs=rsqrtf(var+1e-5f);
  float* op=h+(size_t)n*HIDD+(size_t)sl*6;
  const float* sc=nsc+sl*6;
  const float* bi=nbi+sl*6;
  float o[6];
  #pragma unroll
  for(int c=0;c<6;c++) o[c]=(t[c]-mean)*rs*sc[c]+bi[c];
  *(float2*)(op)  =float2{o[0],o[1]};
  *(float2*)(op+2)=float2{o[2],o[3]};
  *(float2*)(op+4)=float2{o[4],o[5]};
}

// ---------- prediction heads ----------
__global__ __launch_bounds__(256) void k_hd1(const float* __restrict__ h, const int* __restrict__ zone,
    const float* __restrict__ cw1,const float* __restrict__ cb1,
    const float* __restrict__ dw1,const float* __restrict__ db1,
    const float* __restrict__ jw1,const float* __restrict__ jb1,
    float* __restrict__ t1){
  int idx=blockIdx.x*256+threadIdx.x;
  if(idx>=3*NZ*96) return;
  int hd=idx/(NZ*96); int rem=idx-hd*(NZ*96); int row=rem/96; int j=rem-row*96;
  const float* w1=(hd==0)?cw1:((hd==1)?dw1:jw1);
  const float* b1=(hd==0)?cb1:((hd==1)?db1:jb1);
  int n=zone[row];
  const float* hr=h+(size_t)n*96;
  float acc=b1[j];
  #pragma unroll
  for(int k4=0;k4<24;k4++){
    float4 hv=*(const float4*)(hr+k4*4);
    acc+=hv.x*w1[(k4*4+0)*96+j];
    acc+=hv.y*w1[(k4*4+1)*96+j];
    acc+=hv.z*w1[(k4*4+2)*96+j];
    acc+=hv.w*w1[(k4*4+3)*96+j];
  }
  t1[idx]=fmaxf(acc,0.f);
}

__global__ __launch_bounds__(256) void k_hd2(const float* __restrict__ t1,
    const float* __restrict__ cw2,const float* __restrict__ cb2,
    const float* __restrict__ dw2,const float* __restrict__ db2,
    const float* __restrict__ jw2,const float* __restrict__ jb2,
    float* __restrict__ t2){
  int idx=blockIdx.x*256+threadIdx.x;
  if(idx>=3*NZ*48) return;
  int hd=idx/(NZ*48); int rem=idx-hd*(NZ*48); int row=rem/48; int c=rem-row*48;
  const float* w2=(hd==0)?cw2:((hd==1)?dw2:jw2);
  const float* b2=(hd==0)?cb2:((hd==1)?db2:jb2);
  const float* t1r=t1+(size_t)hd*NZ*96+(size_t)row*96;
  float acc=b2[c];
  #pragma unroll
  for(int k4=0;k4<24;k4++){
    float4 tv=*(const float4*)(t1r+k4*4);
    acc+=tv.x*w2[(k4*4+0)*48+c];
    acc+=tv.y*w2[(k4*4+1)*48+c];
    acc+=tv.z*w2[(k4*4+2)*48+c];
    acc+=tv.w*w2[(k4*4+3)*48+c];
  }
  t2[idx]=fmaxf(acc,0.f);
}

__global__ __launch_bounds__(256) void k_hd3(const float* __restrict__ t2,
    const float* __restrict__ cw3,const float* __restrict__ cb3,
    const float* __restrict__ dw3,const float* __restrict__ db3,
    const float* __restrict__ jw3,const float* __restrict__ jb3,
    float* __restrict__ out){
  int idx=blockIdx.x*256+threadIdx.x;
  if(idx>=NZ*4) return;
  int row=idx>>2, o=idx&3;
  int hd=(o<2)?0:((o==2)?1:2);
  int c=(o<2)?o:0;
  int osz=(hd==0)?2:1;
  const float* w3=(hd==0)?cw3:((hd==1)?dw3:jw3);
  const float* b3=(hd==0)?cb3:((hd==1)?db3:jb3);
  const float* t2r=t2+(size_t)hd*NZ*48+(size_t)row*48;
  float acc=b3[c];
  #pragma unroll
  for(int k=0;k<48;k++) acc+=t2r[k]*w3[k*osz+c];
  out[idx]=acc;
}

extern "C" void kernel_launch(void* const* d_in, const int* in_sizes, int n_in,
                              void* d_out, int out_size, void* d_ws, size_t ws_size,
                              hipStream_t stream){
  const float* x       =(const float*)d_in[0];
  const int*   eidx    =(const int*)  d_in[1];
  const float* eattr   =(const float*)d_in[2];
  const int*   zone    =(const int*)  d_in[3];
  const float* in_w1   =(const float*)d_in[4];
  const float* in_b1   =(const float*)d_in[5];
  const float* in_w2   =(const float*)d_in[6];
  const float* in_b2   =(const float*)d_in[7];
  const float* conv_w  =(const float*)d_in[8];
  const float* att_src =(const float*)d_in[9];
  const float* att_dst =(const float*)d_in[10];
  const float* lin_edge=(const float*)d_in[11];
  const float* att_edge=(const float*)d_in[12];
  const float* conv_bias=(const float*)d_in[13];
  const float* nsc     =(const float*)d_in[14];
  const float* nbi     =(const float*)d_in[15];
  float* out=(float*)d_out;

  char* p=(char*)d_ws;
  auto carve=[&](size_t bytes)->char*{ char* r=p; p+=(bytes+255)&~(size_t)255; return r; };
  float*  h    =(float*)carve((size_t)NN*96*4);
  char*   uni  =carve((size_t)NN*96*4);              // union: hid1 fp32 | {hp16, att}
  float*  hid1 =(float*)uni;
  __half* hp16 =(__half*)uni;                         // NN*96*2 = 9.6 MB
  float*  att  =(float*)(uni+(size_t)NN*96*2);        // NN*8*4  = 1.6 MB
  int*    ssrc =(int*)  carve((size_t)EE*4);
  float*  sea  =(float*)carve((size_t)EE*16);
  int*    deg  =(int*)  carve((size_t)NN*4);
  int*    off  =(int*)  carve((size_t)(NN+1)*4);
  int*    cur  =(int*)  carve((size_t)NN*4);
  float*  Watt =(float*)carve((size_t)4*96*8*4);
  float*  Mm   =(float*)carve(64*4);
  int*    part =(int*)  carve(64*4);
  float*  t1b  =(float*)carve((size_t)3*NZ*96*4);
  float*  t2b  =(float*)carve((size_t)3*NZ*48*4);

  const int* srcp=eidx;
  const int* dstp=eidx+EE;

  hipMemsetAsync(deg,0,(size_t)NN*4,stream);
  k_deg<<<EE/256,256,0,stream>>>(dstp,deg);
  k_scan1<<<49,256,0,stream>>>(deg,off,part);
  k_scan2<<<1,64,0,stream>>>(part,off,49);
  k_scan3<<<(NN+255)/256,256,0,stream>>>(part,off,cur);
  k_scatter<<<EE/256,256,0,stream>>>(srcp,dstp,eattr,cur,ssrc,sea);
  k_prepw<<<(4*96*8+64+255)/256,256,0,stream>>>(conv_w,att_src,att_dst,lin_edge,att_edge,Watt,Mm);

  k_mlp1<<<(NN+255)/256,256,0,stream>>>(x,in_w1,in_b1,hid1);
  k_gemm96<false><<<(NN+63)/64,256,0,stream>>>(hid1,96,in_w2,in_b2,h,96);

  for(int l=0;l<4;l++){
    k_gemm96<true><<<(NN+63)/64,256,0,stream>>>(h,96,conv_w+(size_t)l*96*96,nullptr,hp16,96);
    k_att8<<<(NN+255)/256,256,0,stream>>>(h,Watt+(size_t)l*96*8,att);
    k_agg<<<(NN+15)/16,256,0,stream>>>(hp16,att,h,off,ssrc,sea,Mm+l*16,
                                       conv_bias+l*96,nsc+l*96,nbi+l*96);
  }

  k_hd1<<<(3*NZ*96+255)/256,256,0,stream>>>(h,zone,
    (const float*)d_in[16],(const float*)d_in[17],
    (const float*)d_in[22],(const float*)d_in[23],
    (const float*)d_in[28],(const float*)d_in[29], t1b);
  k_hd2<<<(3*NZ*48+255)/256,256,0,stream>>>(t1b,
    (const float*)d_in[18],(const float*)d_in[19],
    (const float*)d_in[24],(const float*)d_in[25],
    (const float*)d_in[30],(const float*)d_in[31], t2b);
  k_hd3<<<(NZ*4+255)/256,256,0,stream>>>(t2b,
    (const float*)d_in[20],(const float*)d_in[21],
    (const float*)d_in[26],(const float*)d_in[27],
    (const float*)d_in[32],(const float*)d_in[33], out);
}